// Round 17
// baseline (116.606 us; speedup 1.0000x reference)
//
#include <hip/hip_runtime.h>
#include <hip/hip_bf16.h>
#include <math.h>

#define NN 1024
#define BB 64
#define LL 197
#define LP 256
#define LBV 13        // valid l-blocks (l < 208 covers LL=197)
#define DD 768

typedef __attribute__((ext_vector_type(8))) short short8;
typedef __attribute__((ext_vector_type(4))) float f32x4;

constexpr float LN_EPS = 1e-5f;
constexpr float NORM_EPS = 1e-12f;
constexpr float EPS = 1e-8f;

__device__ __forceinline__ float waveSum(float v) {
#pragma unroll
    for (int m = 32; m >= 1; m >>= 1) v += __shfl_xor(v, m, 64);
    return v;
}
__device__ __forceinline__ float grpSum(float v) {
#pragma unroll
    for (int m = 8; m >= 1; m >>= 1) v += __shfl_xor(v, m, 64);
    return v;
}
__device__ __forceinline__ float grpMax(float v) {
#pragma unroll
    for (int m = 8; m >= 1; m >>= 1) v = fmaxf(v, __shfl_xor(v, m, 64));
    return v;
}

__device__ __forceinline__ float bf2f(unsigned short u) {
    unsigned int x = ((unsigned int)u) << 16;
    return reinterpret_cast<float&>(x);
}

__device__ __forceinline__ void gl_lds16(const void* g, void* l) {
    __builtin_amdgcn_global_load_lds(
        (const __attribute__((address_space(1))) unsigned int*)g,
        (__attribute__((address_space(3))) unsigned int*)l, 16, 0, 0);
}

// Raw barrier (no compiler-inserted vmcnt(0) drain) + scheduling pin.
__device__ __forceinline__ void raw_barrier() {
    __builtin_amdgcn_sched_barrier(0);
    __builtin_amdgcn_s_barrier();
    __builtin_amdgcn_sched_barrier(0);
}

// Text LayerNorm -> bf16 + qinv = 1/max(||y||,eps)
__global__ __launch_bounds__(256) void ln_kernel(
    const float* __restrict__ x, __hip_bfloat16* __restrict__ y,
    const float* __restrict__ gamma, const float* __restrict__ beta,
    float* __restrict__ qinv) {
    const int row = blockIdx.x;
    const int tid = threadIdx.x;
    const float* xr = x + (size_t)row * DD;
    __hip_bfloat16* yr = y + (size_t)row * DD;

    float v[3];
    float s = 0.f, ss = 0.f;
#pragma unroll
    for (int c = 0; c < 3; c++) {
        float t = xr[tid + 256 * c];
        v[c] = t; s += t; ss += t * t;
    }
    __shared__ float red[8];
    s = waveSum(s); ss = waveSum(ss);
    const int w = tid >> 6;
    if ((tid & 63) == 0) { red[w] = s; red[4 + w] = ss; }
    __syncthreads();
    s = red[0] + red[1] + red[2] + red[3];
    ss = red[4] + red[5] + red[6] + red[7];
    const float mean = s * (1.f / DD);
    const float var = ss * (1.f / DD) - mean * mean;
    const float rs = rsqrtf(var + LN_EPS);

    float q = 0.f;
#pragma unroll
    for (int c = 0; c < 3; c++) {
        const int d = tid + 256 * c;
        float t = (v[c] - mean) * rs * gamma[d] + beta[d];
        __hip_bfloat16 hb = __float2bfloat16(t);
        yr[d] = hb;
        float tb = __bfloat162float(hb);
        q += tb * tb;
    }
    __syncthreads();
    q = waveSum(q);
    if ((tid & 63) == 0) red[w] = q;
    __syncthreads();
    if (tid == 0) {
        float n2 = red[0] + red[1] + red[2] + red[3];
        qinv[row] = 1.f / fmaxf(sqrtf(n2), NORM_EPS);
    }
}

// Vision LayerNorm into padded [B, LP, D]; XCD-swizzled: blockid ≡ b (mod 8).
__global__ __launch_bounds__(256) void ln_vis_kernel(
    const float* __restrict__ x, __hip_bfloat16* __restrict__ y,
    const float* __restrict__ gamma, const float* __restrict__ beta) {
    const int id = blockIdx.x;           // 0..BB*LP-1 (16384)
    const int xcd = id & 7;
    const int k = id >> 3;               // 0..2047
    const int bhi = k >> 8;              // 0..7
    const int l = k & 255;               // 0..255
    const int b = xcd + 8 * bhi;
    const int tid = threadIdx.x;
    __hip_bfloat16* yr = y + ((size_t)b * LP + l) * DD;
    if (l >= LL) {
#pragma unroll
        for (int c = 0; c < 3; c++) yr[tid + 256 * c] = __float2bfloat16(0.f);
        return;
    }
    const float* xr = x + ((size_t)b * LL + l) * DD;

    float v[3];
    float s = 0.f, ss = 0.f;
#pragma unroll
    for (int c = 0; c < 3; c++) {
        float t = xr[tid + 256 * c];
        v[c] = t; s += t; ss += t * t;
    }
    __shared__ float red[8];
    s = waveSum(s); ss = waveSum(ss);
    const int w = tid >> 6;
    if ((tid & 63) == 0) { red[w] = s; red[4 + w] = ss; }
    __syncthreads();
    s = red[0] + red[1] + red[2] + red[3];
    ss = red[4] + red[5] + red[6] + red[7];
    const float mean = s * (1.f / DD);
    const float var = ss * (1.f / DD) - mean * mean;
    const float rs = rsqrtf(var + LN_EPS);
#pragma unroll
    for (int c = 0; c < 3; c++) {
        const int d = tid + 256 * c;
        yr[d] = __float2bfloat16((v[c] - mean) * rs * gamma[d] + beta[d]);
    }
}

// Gram: G[b] = vt_b . vt_b^T, gl_lds triple-buffer + counted vmcnt + raw
// barriers (1/iter). Grid 512 (2/CU exactly), XCD-swizzled. LDS 55296.
__global__ __launch_bounds__(256, 2) void gram_kernel(
    const __hip_bfloat16* __restrict__ vt, __hip_bfloat16* __restrict__ G) {
    const int id = blockIdx.x;           // 0..511
    const int xcd = id & 7;
    const int k = id >> 3;               // 0..63
    const int bhi = k >> 3;              // 0..7
    const int rb = k & 7;                // 0..7
    const int b = xcd + 8 * bhi;
    const int n0 = rb * 32;
    const int tid = threadIdx.x, w = tid >> 6, lane = tid & 63;
    const int g = lane >> 4, c = lane & 15;
    const int gsw = (g ^ ((c ^ (c >> 2)) & 3)) * 16;

    __shared__ __align__(16) unsigned char smem[55296];
    const char* vtbc = (const char*)(vt + (size_t)b * LP * DD);

#define GSTAGE(ks, bsel)                                                        \
    {                                                                           \
        const int kb_ = (ks) * 64;                                              \
        _Pragma("unroll")                                                       \
        for (int q_ = 0; q_ < 4; q_++) {                                        \
            const int o_ = q_ * 4096 + tid * 16;                                \
            const int r_ = o_ >> 6;                                             \
            const int sj_ = ((o_ >> 4) & 3) ^ ((r_ ^ (r_ >> 2)) & 3);           \
            gl_lds16(vtbc + (size_t)r_ * 1536 + kb_ + sj_ * 16,                 \
                     smem + (bsel) * 16384 + q_ * 4096 + w * 1024);             \
        }                                                                       \
        if (w < 2) {                                                            \
            const int o_ = tid * 16;                                            \
            const int r_ = o_ >> 6;                                             \
            const int sj_ = ((o_ >> 4) & 3) ^ ((r_ ^ (r_ >> 2)) & 3);           \
            gl_lds16(vtbc + (size_t)(n0 + r_) * 1536 + kb_ + sj_ * 16,          \
                     smem + 49152 + (bsel) * 2048 + w * 1024);                  \
        }                                                                       \
    }

    f32x4 acc[4][2];
#pragma unroll
    for (int i = 0; i < 4; i++)
#pragma unroll
        for (int nb = 0; nb < 2; nb++) acc[i][nb] = {0.f, 0.f, 0.f, 0.f};

    GSTAGE(0, 0);
    GSTAGE(1, 1);
    asm volatile("s_waitcnt vmcnt(4)" ::: "memory");
    raw_barrier();

    for (int ks = 0; ks < 24; ks++) {
        if (ks < 22) GSTAGE(ks + 2, (ks + 2) % 3);
        const unsigned char* vb = smem + (ks % 3) * 16384;
        const unsigned char* tb = smem + 49152 + (ks % 3) * 2048;
        short8 af[2], bf[4];
#pragma unroll
        for (int nb = 0; nb < 2; nb++)
            af[nb] = *(const short8*)(tb + (nb * 16 + c) * 64 + gsw);
#pragma unroll
        for (int i = 0; i < 4; i++)
            bf[i] = *(const short8*)(vb + ((w + 4 * i) * 16 + c) * 64 + gsw);
#pragma unroll
        for (int i = 0; i < 4; i++)
#pragma unroll
            for (int nb = 0; nb < 2; nb++)
                acc[i][nb] = __builtin_amdgcn_mfma_f32_16x16x32_bf16(
                    af[nb], bf[i], acc[i][nb], 0, 0, 0);
        __builtin_amdgcn_sched_barrier(0);
        if (ks < 22) asm volatile("s_waitcnt vmcnt(4)" ::: "memory");
        else         asm volatile("s_waitcnt vmcnt(0)" ::: "memory");
        raw_barrier();
    }
#undef GSTAGE

    __hip_bfloat16* Gb = G + (size_t)b * LP * LP;
#pragma unroll
    for (int i = 0; i < 4; i++) {
        const int col = (w + 4 * i) * 16 + c;
#pragma unroll
        for (int nb = 0; nb < 2; nb++)
#pragma unroll
            for (int r = 0; r < 4; r++)
                Gb[(size_t)(n0 + nb * 16 + g * 4 + r) * LP + col] =
                    __float2bfloat16(acc[i][nb][r]);
    }
}

// score: S = tf.vt^T over 13 real l-blocks (208 staged vt rows), gl_lds
// TRIPLE-buffer, ONE raw barrier per iter, counted vmcnt. Softmax, num ->
// Pbuf + numq. Grid 1024, XCD-swizzled. (256,3). LDS 52224 -> 3 blocks/CU.
__global__ __launch_bounds__(256, 3) void score_kernel(
    const __hip_bfloat16* __restrict__ tf, const __hip_bfloat16* __restrict__ vt,
    const float* __restrict__ qinv, __hip_bfloat16* __restrict__ Pbuf,
    float* __restrict__ numq) {
    const int id = blockIdx.x;
    const int xcd = id & 7;
    const int kk = id >> 3;              // 0..127
    const int bhi = kk >> 4;             // 0..7
    const int nt = kk & 15;              // 0..15
    const int b = xcd + 8 * bhi;
    const int n0 = nt * 64;
    const int tid = threadIdx.x, w = tid >> 6, lane = tid & 63;
    const int g = lane >> 4, c = lane & 15;
    const int gsw = (g ^ ((c ^ (c >> 2)) & 3)) * 16;

    __shared__ __align__(16) unsigned char smem[52224];
    float* mx = (float*)smem;            // [64][4] overlay (post-stage1)
    float* sm = mx + 256;
    float* nm = sm + 256;

    const char* vtbc = (const char*)(vt + (size_t)b * LP * DD);
    const char* tfc = (const char*)(tf + (size_t)n0 * DD);

// vbuf[bsel] @ bsel*13312 (208 rows x 64B), tbuf[bsel] @ 39936 + bsel*4096.
// 3 full rounds + distributed tail (lanes<16; uniform 5 gl_lds per wave).
#define SSTAGE(ks, bsel)                                                        \
    {                                                                           \
        const int kb_ = (ks) * 64;                                              \
        _Pragma("unroll")                                                       \
        for (int q_ = 0; q_ < 3; q_++) {                                        \
            const int o_ = q_ * 4096 + tid * 16;                                \
            const int r_ = o_ >> 6;                                             \
            const int sj_ = ((o_ >> 4) & 3) ^ ((r_ ^ (r_ >> 2)) & 3);           \
            gl_lds16(vtbc + (size_t)r_ * 1536 + kb_ + sj_ * 16,                 \
                     smem + (bsel) * 13312 + q_ * 4096 + w * 1024);             \
        }                                                                       \
        if (lane < 16) {                                                        \
            const int o_ = 12288 + (w * 16 + lane) * 16;                        \
            const int r_ = o_ >> 6;                                             \
            const int sj_ = ((o_ >> 4) & 3) ^ ((r_ ^ (r_ >> 2)) & 3);           \
            gl_lds16(vtbc + (size_t)r_ * 1536 + kb_ + sj_ * 16,                 \
                     smem + (bsel) * 13312 + 12288 + w * 256);                  \
        }                                                                       \
        {                                                                       \
            const int o_ = tid * 16;                                            \
            const int r_ = o_ >> 6;                                             \
            const int sj_ = ((o_ >> 4) & 3) ^ ((r_ ^ (r_ >> 2)) & 3);           \
            gl_lds16(tfc + (size_t)r_ * 1536 + kb_ + sj_ * 16,                  \
                     smem + 39936 + (bsel) * 4096 + w * 1024);                  \
        }                                                                       \
    }

    f32x4 acc[4][4];
#pragma unroll
    for (int i = 0; i < 4; i++)
#pragma unroll
        for (int nb = 0; nb < 4; nb++) acc[i][nb] = {0.f, 0.f, 0.f, 0.f};

    SSTAGE(0, 0);
    SSTAGE(1, 1);
    asm volatile("s_waitcnt vmcnt(5)" ::: "memory");
    raw_barrier();

    for (int ks = 0; ks < 24; ks++) {
        if (ks < 22) SSTAGE(ks + 2, (ks + 2) % 3);
        const unsigned char* vb = smem + (ks % 3) * 13312;
        const unsigned char* tb = smem + 39936 + (ks % 3) * 4096;
        short8 af[4];
#pragma unroll
        for (int nb = 0; nb < 4; nb++)
            af[nb] = *(const short8*)(tb + (nb * 16 + c) * 64 + gsw);
#pragma unroll
        for (int i = 0; i < 4; i++) {
            const int lb = w + 4 * i;
            if (lb < LBV) {
                short8 bfv = *(const short8*)(vb + (lb * 16 + c) * 64 + gsw);
#pragma unroll
                for (int nb = 0; nb < 4; nb++)
                    acc[i][nb] = __builtin_amdgcn_mfma_f32_16x16x32_bf16(
                        af[nb], bfv, acc[i][nb], 0, 0, 0);
            }
        }
        __builtin_amdgcn_sched_barrier(0);
        if (ks < 22) asm volatile("s_waitcnt vmcnt(5)" ::: "memory");
        else         asm volatile("s_waitcnt vmcnt(0)" ::: "memory");
        raw_barrier();
    }
#undef SSTAGE

    // ---- softmax over l (waves hold disjoint l-columns) ----
    const float inv_sqrtD = 0.0360843918f;
    float mp[4][4];
#pragma unroll
    for (int nb = 0; nb < 4; nb++)
#pragma unroll
        for (int r = 0; r < 4; r++) mp[nb][r] = -1e30f;
#pragma unroll
    for (int i = 0; i < 4; i++) {
        const int l = (w + 4 * i) * 16 + c;
        if (l < LL) {
#pragma unroll
            for (int nb = 0; nb < 4; nb++)
#pragma unroll
                for (int r = 0; r < 4; r++) mp[nb][r] = fmaxf(mp[nb][r], acc[i][nb][r]);
        }
    }
#pragma unroll
    for (int nb = 0; nb < 4; nb++)
#pragma unroll
        for (int r = 0; r < 4; r++) mp[nb][r] = grpMax(mp[nb][r]);
    if (c == 0) {
#pragma unroll
        for (int nb = 0; nb < 4; nb++)
#pragma unroll
            for (int r = 0; r < 4; r++) mx[(nb * 16 + g * 4 + r) * 4 + w] = mp[nb][r];
    }
    __syncthreads();
    float mf[4][4];
#pragma unroll
    for (int nb = 0; nb < 4; nb++)
#pragma unroll
        for (int r = 0; r < 4; r++) {
            const int row = nb * 16 + g * 4 + r;
            mf[nb][r] = fmaxf(fmaxf(mx[row * 4 + 0], mx[row * 4 + 1]),
                              fmaxf(mx[row * 4 + 2], mx[row * 4 + 3]));
        }

    float sp[4][4], np[4][4];
#pragma unroll
    for (int nb = 0; nb < 4; nb++)
#pragma unroll
        for (int r = 0; r < 4; r++) { sp[nb][r] = 0.f; np[nb][r] = 0.f; }
#pragma unroll
    for (int i = 0; i < 4; i++) {
        const int l = (w + 4 * i) * 16 + c;
#pragma unroll
        for (int nb = 0; nb < 4; nb++)
#pragma unroll
            for (int r = 0; r < 4; r++) {
                const float raw = acc[i][nb][r];
                const float p = (l < LL) ? __expf((raw - mf[nb][r]) * inv_sqrtD) : 0.f;
                acc[i][nb][r] = p;
                sp[nb][r] += p;
                np[nb][r] += p * raw;
            }
    }
#pragma unroll
    for (int nb = 0; nb < 4; nb++)
#pragma unroll
        for (int r = 0; r < 4; r++) { sp[nb][r] = grpSum(sp[nb][r]); np[nb][r] = grpSum(np[nb][r]); }
    if (c == 0) {
#pragma unroll
        for (int nb = 0; nb < 4; nb++)
#pragma unroll
            for (int r = 0; r < 4; r++) {
                const int row = nb * 16 + g * 4 + r;
                sm[row * 4 + w] = sp[nb][r];
                nm[row * 4 + w] = np[nb][r];
            }
    }
    __syncthreads();

    float invs[4][4];
#pragma unroll
    for (int nb = 0; nb < 4; nb++)
#pragma unroll
        for (int r = 0; r < 4; r++) {
            const int row = nb * 16 + g * 4 + r;
            const float ssum = sm[row * 4 + 0] + sm[row * 4 + 1] + sm[row * 4 + 2] + sm[row * 4 + 3];
            invs[nb][r] = 1.f / ssum;
        }

    // P write: all 16 l-blocks (invalid/pad blocks hold p=0 -> writes zeros)
    __hip_bfloat16* Pb = Pbuf + ((size_t)b * NN + n0) * LP;
#pragma unroll
    for (int i = 0; i < 4; i++) {
        const int lb = w + 4 * i;
#pragma unroll
        for (int nb = 0; nb < 4; nb++)
#pragma unroll
            for (int r = 0; r < 4; r++)
                Pb[(size_t)(nb * 16 + g * 4 + r) * LP + lb * 16 + c] =
                    __float2bfloat16(acc[i][nb][r] * invs[nb][r]);
    }

    if (tid < 64) {
        const int row = tid;
        const int n = n0 + row;
        const float ssum = sm[row * 4 + 0] + sm[row * 4 + 1] + sm[row * 4 + 2] + sm[row * 4 + 3];
        const float nsum = nm[row * 4 + 0] + nm[row * 4 + 1] + nm[row * 4 + 2] + nm[row * 4 + 3];
        numq[(size_t)n * BB + b] = (nsum / ssum) * qinv[n];
    }
}

// den: T = P.G over 13 col-blocks, K=224 (7 steps), TRIPLE-buffer, 1 barrier
// per iter, counted vmcnt. den = sum P*T, logits. Grid 1024. (256,3). LDS 52224.
__global__ __launch_bounds__(256, 3) void den_kernel(
    const __hip_bfloat16* __restrict__ Pbuf, const __hip_bfloat16* __restrict__ G,
    const float* __restrict__ numq, float* __restrict__ logits) {
    const int id = blockIdx.x;
    const int xcd = id & 7;
    const int kk = id >> 3;
    const int bhi = kk >> 4;
    const int nt = kk & 15;
    const int b = xcd + 8 * bhi;
    const int n0 = nt * 64;
    const int tid = threadIdx.x, w = tid >> 6, lane = tid & 63;
    const int g = lane >> 4, c = lane & 15;
    const int gsw = (g ^ ((c ^ (c >> 2)) & 3)) * 16;

    __shared__ __align__(16) unsigned char smem[52224];
    float* mx = (float*)smem;            // [64][4] overlay (post-GEMM)

    const char* Gbc = (const char*)(G + (size_t)b * LP * LP);
    const char* Pbc = (const char*)(Pbuf + ((size_t)b * NN + n0) * LP);

#define DSTAGE(ks, bsel)                                                        \
    {                                                                           \
        const int kb_ = (ks) * 64;                                              \
        _Pragma("unroll")                                                       \
        for (int q_ = 0; q_ < 3; q_++) {                                        \
            const int o_ = q_ * 4096 + tid * 16;                                \
            const int r_ = o_ >> 6;                                             \
            const int sj_ = ((o_ >> 4) & 3) ^ ((r_ ^ (r_ >> 2)) & 3);           \
            gl_lds16(Gbc + (size_t)r_ * 512 + kb_ + sj_ * 16,                   \
                     smem + (bsel) * 13312 + q_ * 4096 + w * 1024);             \
        }                                                                       \
        if (lane < 16) {                                                        \
            const int o_ = 12288 + (w * 16 + lane) * 16;                        \
            const int r_ = o_ >> 6;                                             \
            const int sj_ = ((o_ >> 4) & 3) ^ ((r_ ^ (r_ >> 2)) & 3);           \
            gl_lds16(Gbc + (size_t)r_ * 512 + kb_ + sj_ * 16,                   \
                     smem + (bsel) * 13312 + 12288 + w * 256);                  \
        }                                                                       \
        {                                                                       \
            const int o_ = tid * 16;                                            \
            const int r_ = o_ >> 6;                                             \
            const int sj_ = ((o_ >> 4) & 3) ^ ((r_ ^ (r_ >> 2)) & 3);           \
            gl_lds16(Pbc + (size_t)r_ * 512 + kb_ + sj_ * 16,                   \
                     smem + 39936 + (bsel) * 4096 + w * 1024);                  \
        }                                                                       \
    }

    f32x4 acc[4][4];
#pragma unroll
    for (int i = 0; i < 4; i++)
#pragma unroll
        for (int nb = 0; nb < 4; nb++) acc[i][nb] = {0.f, 0.f, 0.f, 0.f};

    DSTAGE(0, 0);
    DSTAGE(1, 1);
    asm volatile("s_waitcnt vmcnt(5)" ::: "memory");
    raw_barrier();

    for (int ks = 0; ks < 7; ks++) {
        if (ks < 5) DSTAGE(ks + 2, (ks + 2) % 3);
        const unsigned char* vb = smem + (ks % 3) * 13312;
        const unsigned char* tb = smem + 39936 + (ks % 3) * 4096;
        short8 af[4];
#pragma unroll
        for (int nb = 0; nb < 4; nb++)
            af[nb] = *(const short8*)(tb + (nb * 16 + c) * 64 + gsw);
#pragma unroll
        for (int i = 0; i < 4; i++) {
            const int lb = w + 4 * i;
            if (lb < LBV) {
                short8 bfv = *(const short8*)(vb + (lb * 16 + c) * 64 + gsw);
#pragma unroll
                for (int nb = 0; nb < 4; nb++)
                    acc[i][nb] = __builtin_amdgcn_mfma_f32_16x16x32_bf16(
                        af[nb], bfv, acc[i][nb], 0, 0, 0);
            }
        }
        __builtin_amdgcn_sched_barrier(0);
        if (ks < 5) asm volatile("s_waitcnt vmcnt(5)" ::: "memory");
        else        asm volatile("s_waitcnt vmcnt(0)" ::: "memory");
        raw_barrier();
    }
#undef DSTAGE

    // den = sum over valid cols of P * T (P re-read from L2-hot Pbuf)
    const short* Pb = (const short*)Pbc;
    float den[4][4];
#pragma unroll
    for (int nb = 0; nb < 4; nb++)
#pragma unroll
        for (int r = 0; r < 4; r++) den[nb][r] = 0.f;
#pragma unroll
    for (int i = 0; i < 4; i++) {
        const int lb = w + 4 * i;
        if (lb < LBV) {
            const int col = lb * 16 + c;
#pragma unroll
            for (int nb = 0; nb < 4; nb++)
#pragma unroll
                for (int r = 0; r < 4; r++) {
                    const float P = bf2f((unsigned short)Pb[(size_t)(nb * 16 + g * 4 + r) * LP + col]);
                    den[nb][r] += P * acc[i][nb][r];
                }
        }
    }

#pragma unroll
    for (int nb = 0; nb < 4; nb++)
#pragma unroll
        for (int r = 0; r < 4; r++) den[nb][r] = grpSum(den[nb][r]);
    __syncthreads();
    if (c == 0) {
#pragma unroll
        for (int nb = 0; nb < 4; nb++)
#pragma unroll
            for (int r = 0; r < 4; r++) mx[(nb * 16 + g * 4 + r) * 4 + w] = den[nb][r];
    }
    __syncthreads();
    if (tid < 64) {
        const int row = tid;
        const int n = n0 + row;
        const float dsum = mx[row * 4 + 0] + mx[row * 4 + 1] + mx[row * 4 + 2] + mx[row * 4 + 3];
        const float dn = fmaxf(sqrtf(fmaxf(dsum, 0.f)), NORM_EPS);
        logits[(size_t)n * BB + b] = numq[(size_t)n * BB + b] / dn;
    }
}

__global__ __launch_bounds__(64) void loss_row_kernel(
    const float* __restrict__ logits, const int* __restrict__ gm,
    const float* __restrict__ logtemp, float* __restrict__ scaled,
    float* __restrict__ posv, float* __restrict__ rowloss) {
    const int n = blockIdx.x;
    const int b = threadIdx.x;
    const float invtemp = 1.f / expf(logtemp[0]);
    const float e = expf(logits[(size_t)n * BB + b] * invtemp);
    scaled[(size_t)n * BB + b] = e;
    const float sum = waveSum(e);
    const int g = gm[n];
    const float pos = __shfl(e, g, 64);
    if (b == 0) {
        posv[n] = pos;
        rowloss[n] = -logf(pos / (sum + EPS) + EPS);
    }
}

__global__ __launch_bounds__(256) void colsum_kernel(
    const float* __restrict__ scaled, const int* __restrict__ gm,
    float* __restrict__ colsum, float* __restrict__ poscol) {
    const int b = blockIdx.x;
    const int tid = threadIdx.x;
    float s = 0.f, p = 0.f;
    for (int n = tid; n < NN; n += 256) {
        const float e = scaled[(size_t)n * BB + b];
        s += e;
        if (gm[n] == b) p += e;
    }
    s = waveSum(s); p = waveSum(p);
    __shared__ float red[8];
    const int w = tid >> 6;
    if ((tid & 63) == 0) { red[w] = s; red[4 + w] = p; }
    __syncthreads();
    if (tid == 0) {
        colsum[b] = red[0] + red[1] + red[2] + red[3];
        poscol[b] = red[4] + red[5] + red[6] + red[7];
    }
}

__global__ __launch_bounds__(1024) void final_kernel(
    const float* __restrict__ posv, const float* __restrict__ rowloss,
    const float* __restrict__ colsum, const float* __restrict__ poscol,
    const int* __restrict__ gm, float* __restrict__ out) {
    const int n = threadIdx.x;
    const int g = gm[n];
    const float pos = posv[n];
    const float sum_neg = colsum[g] - poscol[g];
    const float cl = -logf(pos / (pos + sum_neg + EPS) + EPS);
    float v = rowloss[n] + cl;
    v = waveSum(v);
    __shared__ float red[16];
    if ((n & 63) == 0) red[n >> 6] = v;
    __syncthreads();
    if (n == 0) {
        float s = 0.f;
#pragma unroll
        for (int i = 0; i < 16; i++) s += red[i];
        out[0] = s / (2.f * NN);
    }
}

extern "C" void kernel_launch(void* const* d_in, const int* in_sizes, int n_in,
                              void* d_out, int out_size, void* d_ws, size_t ws_size,
                              hipStream_t stream) {
    const float* text = (const float*)d_in[0];
    const float* vis = (const float*)d_in[1];
    const int* gm = (const int*)d_in[2];
    const float* gamma = (const float*)d_in[3];
    const float* beta = (const float*)d_in[4];
    const float* logtemp = (const float*)d_in[5];
    float* out = (float*)d_out;

    char* w = (char*)d_ws;
    __hip_bfloat16* tf = (__hip_bfloat16*)w;             w += (size_t)NN * DD * 2;
    __hip_bfloat16* vt = (__hip_bfloat16*)w;             w += (size_t)BB * LP * DD * 2;
    __hip_bfloat16* G  = (__hip_bfloat16*)w;             w += (size_t)BB * LP * LP * 2;
    __hip_bfloat16* Pbuf = (__hip_bfloat16*)w;           w += (size_t)BB * NN * LP * 2;
    float* qinv    = (float*)w;  w += (size_t)NN * 4;
    float* numq    = (float*)w;  w += (size_t)NN * BB * 4;
    float* logits  = (float*)w;  w += (size_t)NN * BB * 4;
    float* scaled  = (float*)w;  w += (size_t)NN * BB * 4;
    float* posv    = (float*)w;  w += (size_t)NN * 4;
    float* rowloss = (float*)w;  w += (size_t)NN * 4;
    float* colsum  = (float*)w;  w += (size_t)BB * 4;
    float* poscol  = (float*)w;  w += (size_t)BB * 4;

    ln_kernel<<<NN, 256, 0, stream>>>(text, tf, gamma, beta, qinv);
    ln_vis_kernel<<<BB * LP, 256, 0, stream>>>(vis, vt, gamma, beta);

    score_kernel<<<1024, 256, 0, stream>>>(tf, vt, qinv, Pbuf, numq);
    gram_kernel<<<512, 256, 0, stream>>>(vt, G);
    den_kernel<<<1024, 256, 0, stream>>>(Pbuf, G, numq, logits);

    loss_row_kernel<<<NN, 64, 0, stream>>>(logits, gm, logtemp, scaled, posv, rowloss);
    colsum_kernel<<<BB, 256, 0, stream>>>(scaled, gm, colsum, poscol);
    final_kernel<<<1, 1024, 0, stream>>>(posv, rowloss, colsum, poscol, gm, out);
}

// Round 18
// 115.725 us; speedup vs baseline: 1.0076x; 1.0076x over previous
//
#include <hip/hip_runtime.h>
#include <hip/hip_bf16.h>
#include <math.h>

#define NN 1024
#define BB 64
#define LL 197
#define LP 256
#define LBV 13        // valid l-blocks (l < 208 covers LL=197)
#define DD 768

typedef __attribute__((ext_vector_type(8))) short short8;
typedef __attribute__((ext_vector_type(4))) float f32x4;

constexpr float LN_EPS = 1e-5f;
constexpr float NORM_EPS = 1e-12f;
constexpr float EPS = 1e-8f;

__device__ __forceinline__ float waveSum(float v) {
#pragma unroll
    for (int m = 32; m >= 1; m >>= 1) v += __shfl_xor(v, m, 64);
    return v;
}
__device__ __forceinline__ float grpSum(float v) {
#pragma unroll
    for (int m = 8; m >= 1; m >>= 1) v += __shfl_xor(v, m, 64);
    return v;
}
__device__ __forceinline__ float grpMax(float v) {
#pragma unroll
    for (int m = 8; m >= 1; m >>= 1) v = fmaxf(v, __shfl_xor(v, m, 64));
    return v;
}

__device__ __forceinline__ float bf2f(unsigned short u) {
    unsigned int x = ((unsigned int)u) << 16;
    return reinterpret_cast<float&>(x);
}

__device__ __forceinline__ void gl_lds16(const void* g, void* l) {
    __builtin_amdgcn_global_load_lds(
        (const __attribute__((address_space(1))) unsigned int*)g,
        (__attribute__((address_space(3))) unsigned int*)l, 16, 0, 0);
}

// Light barrier: memory-ordering only (no sched pins, no vmcnt(0) drain).
__device__ __forceinline__ void lite_barrier() {
    asm volatile("s_barrier" ::: "memory");
}

// Text LayerNorm -> bf16 + qinv = 1/max(||y||,eps)
__global__ __launch_bounds__(256) void ln_kernel(
    const float* __restrict__ x, __hip_bfloat16* __restrict__ y,
    const float* __restrict__ gamma, const float* __restrict__ beta,
    float* __restrict__ qinv) {
    const int row = blockIdx.x;
    const int tid = threadIdx.x;
    const float* xr = x + (size_t)row * DD;
    __hip_bfloat16* yr = y + (size_t)row * DD;

    float v[3];
    float s = 0.f, ss = 0.f;
#pragma unroll
    for (int c = 0; c < 3; c++) {
        float t = xr[tid + 256 * c];
        v[c] = t; s += t; ss += t * t;
    }
    __shared__ float red[8];
    s = waveSum(s); ss = waveSum(ss);
    const int w = tid >> 6;
    if ((tid & 63) == 0) { red[w] = s; red[4 + w] = ss; }
    __syncthreads();
    s = red[0] + red[1] + red[2] + red[3];
    ss = red[4] + red[5] + red[6] + red[7];
    const float mean = s * (1.f / DD);
    const float var = ss * (1.f / DD) - mean * mean;
    const float rs = rsqrtf(var + LN_EPS);

    float q = 0.f;
#pragma unroll
    for (int c = 0; c < 3; c++) {
        const int d = tid + 256 * c;
        float t = (v[c] - mean) * rs * gamma[d] + beta[d];
        __hip_bfloat16 hb = __float2bfloat16(t);
        yr[d] = hb;
        float tb = __bfloat162float(hb);
        q += tb * tb;
    }
    __syncthreads();
    q = waveSum(q);
    if ((tid & 63) == 0) red[w] = q;
    __syncthreads();
    if (tid == 0) {
        float n2 = red[0] + red[1] + red[2] + red[3];
        qinv[row] = 1.f / fmaxf(sqrtf(n2), NORM_EPS);
    }
}

// Vision LayerNorm into padded [B, LP, D]; XCD-swizzled: blockid ≡ b (mod 8).
__global__ __launch_bounds__(256) void ln_vis_kernel(
    const float* __restrict__ x, __hip_bfloat16* __restrict__ y,
    const float* __restrict__ gamma, const float* __restrict__ beta) {
    const int id = blockIdx.x;           // 0..BB*LP-1 (16384)
    const int xcd = id & 7;
    const int k = id >> 3;               // 0..2047
    const int bhi = k >> 8;              // 0..7
    const int l = k & 255;               // 0..255
    const int b = xcd + 8 * bhi;
    const int tid = threadIdx.x;
    __hip_bfloat16* yr = y + ((size_t)b * LP + l) * DD;
    if (l >= LL) {
#pragma unroll
        for (int c = 0; c < 3; c++) yr[tid + 256 * c] = __float2bfloat16(0.f);
        return;
    }
    const float* xr = x + ((size_t)b * LL + l) * DD;

    float v[3];
    float s = 0.f, ss = 0.f;
#pragma unroll
    for (int c = 0; c < 3; c++) {
        float t = xr[tid + 256 * c];
        v[c] = t; s += t; ss += t * t;
    }
    __shared__ float red[8];
    s = waveSum(s); ss = waveSum(ss);
    const int w = tid >> 6;
    if ((tid & 63) == 0) { red[w] = s; red[4 + w] = ss; }
    __syncthreads();
    s = red[0] + red[1] + red[2] + red[3];
    ss = red[4] + red[5] + red[6] + red[7];
    const float mean = s * (1.f / DD);
    const float var = ss * (1.f / DD) - mean * mean;
    const float rs = rsqrtf(var + LN_EPS);
#pragma unroll
    for (int c = 0; c < 3; c++) {
        const int d = tid + 256 * c;
        yr[d] = __float2bfloat16((v[c] - mean) * rs * gamma[d] + beta[d]);
    }
}

// Gram: G[b] = vt_b . vt_b^T, gl_lds triple-buffer + counted vmcnt + light
// barriers (1/iter). Grid 512 (2/CU exactly), XCD-swizzled. LDS 55296.
__global__ __launch_bounds__(256, 2) void gram_kernel(
    const __hip_bfloat16* __restrict__ vt, __hip_bfloat16* __restrict__ G) {
    const int id = blockIdx.x;           // 0..511
    const int xcd = id & 7;
    const int k = id >> 3;               // 0..63
    const int bhi = k >> 3;              // 0..7
    const int rb = k & 7;                // 0..7
    const int b = xcd + 8 * bhi;
    const int n0 = rb * 32;
    const int tid = threadIdx.x, w = tid >> 6, lane = tid & 63;
    const int g = lane >> 4, c = lane & 15;
    const int gsw = (g ^ ((c ^ (c >> 2)) & 3)) * 16;

    __shared__ __align__(16) unsigned char smem[55296];
    const char* vtbc = (const char*)(vt + (size_t)b * LP * DD);

#define GSTAGE(ks, bsel)                                                        \
    {                                                                           \
        const int kb_ = (ks) * 64;                                              \
        _Pragma("unroll")                                                       \
        for (int q_ = 0; q_ < 4; q_++) {                                        \
            const int o_ = q_ * 4096 + tid * 16;                                \
            const int r_ = o_ >> 6;                                             \
            const int sj_ = ((o_ >> 4) & 3) ^ ((r_ ^ (r_ >> 2)) & 3);           \
            gl_lds16(vtbc + (size_t)r_ * 1536 + kb_ + sj_ * 16,                 \
                     smem + (bsel) * 16384 + q_ * 4096 + w * 1024);             \
        }                                                                       \
        if (w < 2) {                                                            \
            const int o_ = tid * 16;                                            \
            const int r_ = o_ >> 6;                                             \
            const int sj_ = ((o_ >> 4) & 3) ^ ((r_ ^ (r_ >> 2)) & 3);           \
            gl_lds16(vtbc + (size_t)(n0 + r_) * 1536 + kb_ + sj_ * 16,          \
                     smem + 49152 + (bsel) * 2048 + w * 1024);                  \
        }                                                                       \
    }

    f32x4 acc[4][2];
#pragma unroll
    for (int i = 0; i < 4; i++)
#pragma unroll
        for (int nb = 0; nb < 2; nb++) acc[i][nb] = {0.f, 0.f, 0.f, 0.f};

    GSTAGE(0, 0);
    GSTAGE(1, 1);
    asm volatile("s_waitcnt vmcnt(4)" ::: "memory");
    lite_barrier();

    for (int ks = 0; ks < 24; ks++) {
        if (ks < 22) GSTAGE(ks + 2, (ks + 2) % 3);
        const unsigned char* vb = smem + (ks % 3) * 16384;
        const unsigned char* tb = smem + 49152 + (ks % 3) * 2048;
        short8 af[2], bf[4];
#pragma unroll
        for (int nb = 0; nb < 2; nb++)
            af[nb] = *(const short8*)(tb + (nb * 16 + c) * 64 + gsw);
#pragma unroll
        for (int i = 0; i < 4; i++)
            bf[i] = *(const short8*)(vb + ((w + 4 * i) * 16 + c) * 64 + gsw);
#pragma unroll
        for (int i = 0; i < 4; i++)
#pragma unroll
            for (int nb = 0; nb < 2; nb++)
                acc[i][nb] = __builtin_amdgcn_mfma_f32_16x16x32_bf16(
                    af[nb], bf[i], acc[i][nb], 0, 0, 0);
        if (ks < 22) asm volatile("s_waitcnt vmcnt(4)" ::: "memory");
        else         asm volatile("s_waitcnt vmcnt(0)" ::: "memory");
        lite_barrier();
    }
#undef GSTAGE

    __hip_bfloat16* Gb = G + (size_t)b * LP * LP;
#pragma unroll
    for (int i = 0; i < 4; i++) {
        const int col = (w + 4 * i) * 16 + c;
#pragma unroll
        for (int nb = 0; nb < 2; nb++)
#pragma unroll
            for (int r = 0; r < 4; r++)
                Gb[(size_t)(n0 + nb * 16 + g * 4 + r) * LP + col] =
                    __float2bfloat16(acc[i][nb][r]);
    }
}

// score: S = tf.vt^T over 13 real l-blocks (208 staged vt rows), gl_lds
// double-buffer, counted vmcnt, light barriers. Softmax, num -> Pbuf + numq.
// Grid 1024, XCD-swizzled. (256,3). LDS 34816 -> 4 blocks/CU.
__global__ __launch_bounds__(256, 3) void score_kernel(
    const __hip_bfloat16* __restrict__ tf, const __hip_bfloat16* __restrict__ vt,
    const float* __restrict__ qinv, __hip_bfloat16* __restrict__ Pbuf,
    float* __restrict__ numq) {
    const int id = blockIdx.x;
    const int xcd = id & 7;
    const int kk = id >> 3;              // 0..127
    const int bhi = kk >> 4;             // 0..7
    const int nt = kk & 15;              // 0..15
    const int b = xcd + 8 * bhi;
    const int n0 = nt * 64;
    const int tid = threadIdx.x, w = tid >> 6, lane = tid & 63;
    const int g = lane >> 4, c = lane & 15;
    const int gsw = (g ^ ((c ^ (c >> 2)) & 3)) * 16;

    __shared__ __align__(16) unsigned char smem[34816];
    float* mx = (float*)smem;            // [64][4] overlay (post-stage1)
    float* sm = mx + 256;
    float* nm = sm + 256;

    const char* vtbc = (const char*)(vt + (size_t)b * LP * DD);
    const char* tfc = (const char*)(tf + (size_t)n0 * DD);

// vbuf[bsel] @ bsel*13312 (208 rows x 64B), tbuf[bsel] @ 26624 + bsel*4096.
// 3 full rounds + distributed tail (lanes<16; uniform 5 gl_lds per wave).
#define SSTAGE(ks, bsel)                                                        \
    {                                                                           \
        const int kb_ = (ks) * 64;                                              \
        _Pragma("unroll")                                                       \
        for (int q_ = 0; q_ < 3; q_++) {                                        \
            const int o_ = q_ * 4096 + tid * 16;                                \
            const int r_ = o_ >> 6;                                             \
            const int sj_ = ((o_ >> 4) & 3) ^ ((r_ ^ (r_ >> 2)) & 3);           \
            gl_lds16(vtbc + (size_t)r_ * 1536 + kb_ + sj_ * 16,                 \
                     smem + (bsel) * 13312 + q_ * 4096 + w * 1024);             \
        }                                                                       \
        if (lane < 16) {                                                        \
            const int o_ = 12288 + (w * 16 + lane) * 16;                        \
            const int r_ = o_ >> 6;                                             \
            const int sj_ = ((o_ >> 4) & 3) ^ ((r_ ^ (r_ >> 2)) & 3);           \
            gl_lds16(vtbc + (size_t)r_ * 1536 + kb_ + sj_ * 16,                 \
                     smem + (bsel) * 13312 + 12288 + w * 256);                  \
        }                                                                       \
        {                                                                       \
            const int o_ = tid * 16;                                            \
            const int r_ = o_ >> 6;                                             \
            const int sj_ = ((o_ >> 4) & 3) ^ ((r_ ^ (r_ >> 2)) & 3);           \
            gl_lds16(tfc + (size_t)r_ * 1536 + kb_ + sj_ * 16,                  \
                     smem + 26624 + (bsel) * 4096 + w * 1024);                  \
        }                                                                       \
    }

    f32x4 acc[4][4];
#pragma unroll
    for (int i = 0; i < 4; i++)
#pragma unroll
        for (int nb = 0; nb < 4; nb++) acc[i][nb] = {0.f, 0.f, 0.f, 0.f};

    SSTAGE(0, 0);
    SSTAGE(1, 1);
    asm volatile("s_waitcnt vmcnt(5)" ::: "memory");
    lite_barrier();

    for (int ks = 0; ks < 24; ks++) {
        const unsigned char* vb = smem + (ks & 1) * 13312;
        const unsigned char* tb = smem + 26624 + (ks & 1) * 4096;
        short8 af[4];
#pragma unroll
        for (int nb = 0; nb < 4; nb++)
            af[nb] = *(const short8*)(tb + (nb * 16 + c) * 64 + gsw);
#pragma unroll
        for (int i = 0; i < 4; i++) {
            const int lb = w + 4 * i;
            if (lb < LBV) {
                short8 bfv = *(const short8*)(vb + (lb * 16 + c) * 64 + gsw);
#pragma unroll
                for (int nb = 0; nb < 4; nb++)
                    acc[i][nb] = __builtin_amdgcn_mfma_f32_16x16x32_bf16(
                        af[nb], bfv, acc[i][nb], 0, 0, 0);
            }
        }
        lite_barrier();
        if (ks < 22) {
            SSTAGE(ks + 2, ks & 1);
            asm volatile("s_waitcnt vmcnt(5)" ::: "memory");
        } else {
            asm volatile("s_waitcnt vmcnt(0)" ::: "memory");
        }
        lite_barrier();
    }
#undef SSTAGE

    // ---- softmax over l (waves hold disjoint l-columns) ----
    const float inv_sqrtD = 0.0360843918f;
    float mp[4][4];
#pragma unroll
    for (int nb = 0; nb < 4; nb++)
#pragma unroll
        for (int r = 0; r < 4; r++) mp[nb][r] = -1e30f;
#pragma unroll
    for (int i = 0; i < 4; i++) {
        const int l = (w + 4 * i) * 16 + c;
        if (l < LL) {
#pragma unroll
            for (int nb = 0; nb < 4; nb++)
#pragma unroll
                for (int r = 0; r < 4; r++) mp[nb][r] = fmaxf(mp[nb][r], acc[i][nb][r]);
        }
    }
#pragma unroll
    for (int nb = 0; nb < 4; nb++)
#pragma unroll
        for (int r = 0; r < 4; r++) mp[nb][r] = grpMax(mp[nb][r]);
    if (c == 0) {
#pragma unroll
        for (int nb = 0; nb < 4; nb++)
#pragma unroll
            for (int r = 0; r < 4; r++) mx[(nb * 16 + g * 4 + r) * 4 + w] = mp[nb][r];
    }
    __syncthreads();
    float mf[4][4];
#pragma unroll
    for (int nb = 0; nb < 4; nb++)
#pragma unroll
        for (int r = 0; r < 4; r++) {
            const int row = nb * 16 + g * 4 + r;
            mf[nb][r] = fmaxf(fmaxf(mx[row * 4 + 0], mx[row * 4 + 1]),
                              fmaxf(mx[row * 4 + 2], mx[row * 4 + 3]));
        }

    float sp[4][4], np[4][4];
#pragma unroll
    for (int nb = 0; nb < 4; nb++)
#pragma unroll
        for (int r = 0; r < 4; r++) { sp[nb][r] = 0.f; np[nb][r] = 0.f; }
#pragma unroll
    for (int i = 0; i < 4; i++) {
        const int l = (w + 4 * i) * 16 + c;
#pragma unroll
        for (int nb = 0; nb < 4; nb++)
#pragma unroll
            for (int r = 0; r < 4; r++) {
                const float raw = acc[i][nb][r];
                const float p = (l < LL) ? __expf((raw - mf[nb][r]) * inv_sqrtD) : 0.f;
                acc[i][nb][r] = p;
                sp[nb][r] += p;
                np[nb][r] += p * raw;
            }
    }
#pragma unroll
    for (int nb = 0; nb < 4; nb++)
#pragma unroll
        for (int r = 0; r < 4; r++) { sp[nb][r] = grpSum(sp[nb][r]); np[nb][r] = grpSum(np[nb][r]); }
    if (c == 0) {
#pragma unroll
        for (int nb = 0; nb < 4; nb++)
#pragma unroll
            for (int r = 0; r < 4; r++) {
                const int row = nb * 16 + g * 4 + r;
                sm[row * 4 + w] = sp[nb][r];
                nm[row * 4 + w] = np[nb][r];
            }
    }
    __syncthreads();

    float invs[4][4];
#pragma unroll
    for (int nb = 0; nb < 4; nb++)
#pragma unroll
        for (int r = 0; r < 4; r++) {
            const int row = nb * 16 + g * 4 + r;
            const float ssum = sm[row * 4 + 0] + sm[row * 4 + 1] + sm[row * 4 + 2] + sm[row * 4 + 3];
            invs[nb][r] = 1.f / ssum;
        }

    // P write: all 16 l-blocks (invalid/pad blocks hold p=0 -> writes zeros)
    __hip_bfloat16* Pb = Pbuf + ((size_t)b * NN + n0) * LP;
#pragma unroll
    for (int i = 0; i < 4; i++) {
        const int lb = w + 4 * i;
#pragma unroll
        for (int nb = 0; nb < 4; nb++)
#pragma unroll
            for (int r = 0; r < 4; r++)
                Pb[(size_t)(nb * 16 + g * 4 + r) * LP + lb * 16 + c] =
                    __float2bfloat16(acc[i][nb][r] * invs[nb][r]);
    }

    if (tid < 64) {
        const int row = tid;
        const int n = n0 + row;
        const float ssum = sm[row * 4 + 0] + sm[row * 4 + 1] + sm[row * 4 + 2] + sm[row * 4 + 3];
        const float nsum = nm[row * 4 + 0] + nm[row * 4 + 1] + nm[row * 4 + 2] + nm[row * 4 + 3];
        numq[(size_t)n * BB + b] = (nsum / ssum) * qinv[n];
    }
}

// den: T = P.G over 13 col-blocks, K=224 (7 steps), double-buffer, counted
// vmcnt, light barriers. den = sum P*T, logits. Grid 1024. (256,3). LDS 34816.
__global__ __launch_bounds__(256, 3) void den_kernel(
    const __hip_bfloat16* __restrict__ Pbuf, const __hip_bfloat16* __restrict__ G,
    const float* __restrict__ numq, float* __restrict__ logits) {
    const int id = blockIdx.x;
    const int xcd = id & 7;
    const int kk = id >> 3;
    const int bhi = kk >> 4;
    const int nt = kk & 15;
    const int b = xcd + 8 * bhi;
    const int n0 = nt * 64;
    const int tid = threadIdx.x, w = tid >> 6, lane = tid & 63;
    const int g = lane >> 4, c = lane & 15;
    const int gsw = (g ^ ((c ^ (c >> 2)) & 3)) * 16;

    __shared__ __align__(16) unsigned char smem[34816];
    float* mx = (float*)smem;            // [64][4] overlay (post-GEMM)

    const char* Gbc = (const char*)(G + (size_t)b * LP * LP);
    const char* Pbc = (const char*)(Pbuf + ((size_t)b * NN + n0) * LP);

#define DSTAGE(ks, bsel)                                                        \
    {                                                                           \
        const int kb_ = (ks) * 64;                                              \
        _Pragma("unroll")                                                       \
        for (int q_ = 0; q_ < 3; q_++) {                                        \
            const int o_ = q_ * 4096 + tid * 16;                                \
            const int r_ = o_ >> 6;                                             \
            const int sj_ = ((o_ >> 4) & 3) ^ ((r_ ^ (r_ >> 2)) & 3);           \
            gl_lds16(Gbc + (size_t)r_ * 512 + kb_ + sj_ * 16,                   \
                     smem + (bsel) * 13312 + q_ * 4096 + w * 1024);             \
        }                                                                       \
        if (lane < 16) {                                                        \
            const int o_ = 12288 + (w * 16 + lane) * 16;                        \
            const int r_ = o_ >> 6;                                             \
            const int sj_ = ((o_ >> 4) & 3) ^ ((r_ ^ (r_ >> 2)) & 3);           \
            gl_lds16(Gbc + (size_t)r_ * 512 + kb_ + sj_ * 16,                   \
                     smem + (bsel) * 13312 + 12288 + w * 256);                  \
        }                                                                       \
        {                                                                       \
            const int o_ = tid * 16;                                            \
            const int r_ = o_ >> 6;                                             \
            const int sj_ = ((o_ >> 4) & 3) ^ ((r_ ^ (r_ >> 2)) & 3);           \
            gl_lds16(Pbc + (size_t)r_ * 512 + kb_ + sj_ * 16,                   \
                     smem + 26624 + (bsel) * 4096 + w * 1024);                  \
        }                                                                       \
    }

    f32x4 acc[4][4];
#pragma unroll
    for (int i = 0; i < 4; i++)
#pragma unroll
        for (int nb = 0; nb < 4; nb++) acc[i][nb] = {0.f, 0.f, 0.f, 0.f};

    DSTAGE(0, 0);
    DSTAGE(1, 1);
    asm volatile("s_waitcnt vmcnt(5)" ::: "memory");
    lite_barrier();

    for (int ks = 0; ks < 7; ks++) {
        const unsigned char* vb = smem + (ks & 1) * 13312;
        const unsigned char* tb = smem + 26624 + (ks & 1) * 4096;
        short8 af[4];
#pragma unroll
        for (int nb = 0; nb < 4; nb++)
            af[nb] = *(const short8*)(tb + (nb * 16 + c) * 64 + gsw);
#pragma unroll
        for (int i = 0; i < 4; i++) {
            const int lb = w + 4 * i;
            if (lb < LBV) {
                short8 bfv = *(const short8*)(vb + (lb * 16 + c) * 64 + gsw);
#pragma unroll
                for (int nb = 0; nb < 4; nb++)
                    acc[i][nb] = __builtin_amdgcn_mfma_f32_16x16x32_bf16(
                        af[nb], bfv, acc[i][nb], 0, 0, 0);
            }
        }
        lite_barrier();
        if (ks < 5) {
            DSTAGE(ks + 2, ks & 1);
            asm volatile("s_waitcnt vmcnt(5)" ::: "memory");
        } else {
            asm volatile("s_waitcnt vmcnt(0)" ::: "memory");
        }
        lite_barrier();
    }
#undef DSTAGE

    // den = sum over valid cols of P * T (P re-read from L2-hot Pbuf)
    const short* Pb = (const short*)Pbc;
    float den[4][4];
#pragma unroll
    for (int nb = 0; nb < 4; nb++)
#pragma unroll
        for (int r = 0; r < 4; r++) den[nb][r] = 0.f;
#pragma unroll
    for (int i = 0; i < 4; i++) {
        const int lb = w + 4 * i;
        if (lb < LBV) {
            const int col = lb * 16 + c;
#pragma unroll
            for (int nb = 0; nb < 4; nb++)
#pragma unroll
                for (int r = 0; r < 4; r++) {
                    const float P = bf2f((unsigned short)Pb[(size_t)(nb * 16 + g * 4 + r) * LP + col]);
                    den[nb][r] += P * acc[i][nb][r];
                }
        }
    }

#pragma unroll
    for (int nb = 0; nb < 4; nb++)
#pragma unroll
        for (int r = 0; r < 4; r++) den[nb][r] = grpSum(den[nb][r]);
    __syncthreads();
    if (c == 0) {
#pragma unroll
        for (int nb = 0; nb < 4; nb++)
#pragma unroll
            for (int r = 0; r < 4; r++) mx[(nb * 16 + g * 4 + r) * 4 + w] = den[nb][r];
    }
    __syncthreads();
    if (tid < 64) {
        const int row = tid;
        const int n = n0 + row;
        const float dsum = mx[row * 4 + 0] + mx[row * 4 + 1] + mx[row * 4 + 2] + mx[row * 4 + 3];
        const float dn = fmaxf(sqrtf(fmaxf(dsum, 0.f)), NORM_EPS);
        logits[(size_t)n * BB + b] = numq[(size_t)n * BB + b] / dn;
    }
}

__global__ __launch_bounds__(64) void loss_row_kernel(
    const float* __restrict__ logits, const int* __restrict__ gm,
    const float* __restrict__ logtemp, float* __restrict__ scaled,
    float* __restrict__ posv, float* __restrict__ rowloss) {
    const int n = blockIdx.x;
    const int b = threadIdx.x;
    const float invtemp = 1.f / expf(logtemp[0]);
    const float e = expf(logits[(size_t)n * BB + b] * invtemp);
    scaled[(size_t)n * BB + b] = e;
    const float sum = waveSum(e);
    const int g = gm[n];
    const float pos = __shfl(e, g, 64);
    if (b == 0) {
        posv[n] = pos;
        rowloss[n] = -logf(pos / (sum + EPS) + EPS);
    }
}

__global__ __launch_bounds__(256) void colsum_kernel(
    const float* __restrict__ scaled, const int* __restrict__ gm,
    float* __restrict__ colsum, float* __restrict__ poscol) {
    const int b = blockIdx.x;
    const int tid = threadIdx.x;
    float s = 0.f, p = 0.f;
    for (int n = tid; n < NN; n += 256) {
        const float e = scaled[(size_t)n * BB + b];
        s += e;
        if (gm[n] == b) p += e;
    }
    s = waveSum(s); p = waveSum(p);
    __shared__ float red[8];
    const int w = tid >> 6;
    if ((tid & 63) == 0) { red[w] = s; red[4 + w] = p; }
    __syncthreads();
    if (tid == 0) {
        colsum[b] = red[0] + red[1] + red[2] + red[3];
        poscol[b] = red[4] + red[5] + red[6] + red[7];
    }
}

__global__ __launch_bounds__(1024) void final_kernel(
    const float* __restrict__ posv, const float* __restrict__ rowloss,
    const float* __restrict__ colsum, const float* __restrict__ poscol,
    const int* __restrict__ gm, float* __restrict__ out) {
    const int n = threadIdx.x;
    const int g = gm[n];
    const float pos = posv[n];
    const float sum_neg = colsum[g] - poscol[g];
    const float cl = -logf(pos / (pos + sum_neg + EPS) + EPS);
    float v = rowloss[n] + cl;
    v = waveSum(v);
    __shared__ float red[16];
    if ((n & 63) == 0) red[n >> 6] = v;
    __syncthreads();
    if (n == 0) {
        float s = 0.f;
#pragma unroll
        for (int i = 0; i < 16; i++) s += red[i];
        out[0] = s / (2.f * NN);
    }
}

extern "C" void kernel_launch(void* const* d_in, const int* in_sizes, int n_in,
                              void* d_out, int out_size, void* d_ws, size_t ws_size,
                              hipStream_t stream) {
    const float* text = (const float*)d_in[0];
    const float* vis = (const float*)d_in[1];
    const int* gm = (const int*)d_in[2];
    const float* gamma = (const float*)d_in[3];
    const float* beta = (const float*)d_in[4];
    const float* logtemp = (const float*)d_in[5];
    float* out = (float*)d_out;

    char* w = (char*)d_ws;
    __hip_bfloat16* tf = (__hip_bfloat16*)w;             w += (size_t)NN * DD * 2;
    __hip_bfloat16* vt = (__hip_bfloat16*)w;             w += (size_t)BB * LP * DD * 2;
    __hip_bfloat16* G  = (__hip_bfloat16*)w;             w += (size_t)BB * LP * LP * 2;
    __hip_bfloat16* Pbuf = (__hip_bfloat16*)w;           w += (size_t)BB * NN * LP * 2;
    float* qinv    = (float*)w;  w += (size_t)NN * 4;
    float* numq    = (float*)w;  w += (size_t)NN * BB * 4;
    float* logits  = (float*)w;  w += (size_t)NN * BB * 4;
    float* scaled  = (float*)w;  w += (size_t)NN * BB * 4;
    float* posv    = (float*)w;  w += (size_t)NN * 4;
    float* rowloss = (float*)w;  w += (size_t)NN * 4;
    float* colsum  = (float*)w;  w += (size_t)BB * 4;
    float* poscol  = (float*)w;  w += (size_t)BB * 4;

    ln_kernel<<<NN, 256, 0, stream>>>(text, tf, gamma, beta, qinv);
    ln_vis_kernel<<<BB * LP, 256, 0, stream>>>(vis, vt, gamma, beta);

    score_kernel<<<1024, 256, 0, stream>>>(tf, vt, qinv, Pbuf, numq);
    gram_kernel<<<512, 256, 0, stream>>>(vt, G);
    den_kernel<<<1024, 256, 0, stream>>>(Pbuf, G, numq, logits);

    loss_row_kernel<<<NN, 64, 0, stream>>>(logits, gm, logtemp, scaled, posv, rowloss);
    colsum_kernel<<<BB, 256, 0, stream>>>(scaled, gm, colsum, poscol);
    final_kernel<<<1, 1024, 0, stream>>>(posv, rowloss, colsum, poscol, gm, out);
}

// Round 19
// 112.997 us; speedup vs baseline: 1.0319x; 1.0241x over previous
//
#include <hip/hip_runtime.h>
#include <hip/hip_bf16.h>
#include <math.h>

#define NN 1024
#define BB 64
#define LL 197
#define LP 256
#define LBV 13        // valid l-blocks (l < 208 covers LL=197)
#define DD 768

typedef __attribute__((ext_vector_type(8))) short short8;
typedef __attribute__((ext_vector_type(4))) float f32x4;

constexpr float LN_EPS = 1e-5f;
constexpr float NORM_EPS = 1e-12f;
constexpr float EPS = 1e-8f;

__device__ __forceinline__ float waveSum(float v) {
#pragma unroll
    for (int m = 32; m >= 1; m >>= 1) v += __shfl_xor(v, m, 64);
    return v;
}
__device__ __forceinline__ float grpSum(float v) {
#pragma unroll
    for (int m = 8; m >= 1; m >>= 1) v += __shfl_xor(v, m, 64);
    return v;
}
__device__ __forceinline__ float grpMax(float v) {
#pragma unroll
    for (int m = 8; m >= 1; m >>= 1) v = fmaxf(v, __shfl_xor(v, m, 64));
    return v;
}

__device__ __forceinline__ float bf2f(unsigned short u) {
    unsigned int x = ((unsigned int)u) << 16;
    return reinterpret_cast<float&>(x);
}

__device__ __forceinline__ void gl_lds16(const void* g, void* l) {
    __builtin_amdgcn_global_load_lds(
        (const __attribute__((address_space(1))) unsigned int*)g,
        (__attribute__((address_space(3))) unsigned int*)l, 16, 0, 0);
}

// Light barrier: memory-ordering only (no sched pins, no vmcnt(0) drain).
__device__ __forceinline__ void lite_barrier() {
    asm volatile("s_barrier" ::: "memory");
}

// Text LayerNorm -> bf16 K-tiled tf_t[24][NN][32] + qinv
__global__ __launch_bounds__(256) void ln_kernel(
    const float* __restrict__ x, __hip_bfloat16* __restrict__ y,
    const float* __restrict__ gamma, const float* __restrict__ beta,
    float* __restrict__ qinv) {
    const int row = blockIdx.x;
    const int tid = threadIdx.x;
    const float* xr = x + (size_t)row * DD;

    float v[3];
    float s = 0.f, ss = 0.f;
#pragma unroll
    for (int c = 0; c < 3; c++) {
        float t = xr[tid + 256 * c];
        v[c] = t; s += t; ss += t * t;
    }
    __shared__ float red[8];
    s = waveSum(s); ss = waveSum(ss);
    const int w = tid >> 6;
    if ((tid & 63) == 0) { red[w] = s; red[4 + w] = ss; }
    __syncthreads();
    s = red[0] + red[1] + red[2] + red[3];
    ss = red[4] + red[5] + red[6] + red[7];
    const float mean = s * (1.f / DD);
    const float var = ss * (1.f / DD) - mean * mean;
    const float rs = rsqrtf(var + LN_EPS);

    float q = 0.f;
#pragma unroll
    for (int c = 0; c < 3; c++) {
        const int d = tid + 256 * c;
        float t = (v[c] - mean) * rs * gamma[d] + beta[d];
        __hip_bfloat16 hb = __float2bfloat16(t);
        y[((size_t)(d >> 5) * NN + row) * 32 + (d & 31)] = hb;
        float tb = __bfloat162float(hb);
        q += tb * tb;
    }
    __syncthreads();
    q = waveSum(q);
    if ((tid & 63) == 0) red[w] = q;
    __syncthreads();
    if (tid == 0) {
        float n2 = red[0] + red[1] + red[2] + red[3];
        qinv[row] = 1.f / fmaxf(sqrtf(n2), NORM_EPS);
    }
}

// Vision LayerNorm -> bf16 K-tiled vt_t[B][24][LP][32]; pad rows zero.
__global__ __launch_bounds__(256) void ln_vis_kernel(
    const float* __restrict__ x, __hip_bfloat16* __restrict__ y,
    const float* __restrict__ gamma, const float* __restrict__ beta) {
    const int id = blockIdx.x;           // 0..BB*LP-1
    const int xcd = id & 7;
    const int k = id >> 3;
    const int bhi = k >> 8;
    const int l = k & 255;
    const int b = xcd + 8 * bhi;
    const int tid = threadIdx.x;
    if (l >= LL) {
#pragma unroll
        for (int c = 0; c < 3; c++) {
            const int d = tid + 256 * c;
            y[(((size_t)b * 24 + (d >> 5)) * LP + l) * 32 + (d & 31)] = __float2bfloat16(0.f);
        }
        return;
    }
    const float* xr = x + ((size_t)b * LL + l) * DD;

    float v[3];
    float s = 0.f, ss = 0.f;
#pragma unroll
    for (int c = 0; c < 3; c++) {
        float t = xr[tid + 256 * c];
        v[c] = t; s += t; ss += t * t;
    }
    __shared__ float red[8];
    s = waveSum(s); ss = waveSum(ss);
    const int w = tid >> 6;
    if ((tid & 63) == 0) { red[w] = s; red[4 + w] = ss; }
    __syncthreads();
    s = red[0] + red[1] + red[2] + red[3];
    ss = red[4] + red[5] + red[6] + red[7];
    const float mean = s * (1.f / DD);
    const float var = ss * (1.f / DD) - mean * mean;
    const float rs = rsqrtf(var + LN_EPS);
#pragma unroll
    for (int c = 0; c < 3; c++) {
        const int d = tid + 256 * c;
        y[(((size_t)b * 24 + (d >> 5)) * LP + l) * 32 + (d & 31)] =
            __float2bfloat16((v[c] - mean) * rs * gamma[d] + beta[d]);
    }
}

// Gram: G_t[b][8][LP][32] = vt.vt^T, contiguous-tile staging, triple-buffer,
// counted vmcnt, 1 light barrier/iter. Grid 512, XCD-swizzled. LDS 49152.
__global__ __launch_bounds__(256, 2) void gram_kernel(
    const __hip_bfloat16* __restrict__ vt_t, __hip_bfloat16* __restrict__ G_t) {
    const int id = blockIdx.x;           // 0..511
    const int xcd = id & 7;
    const int k = id >> 3;
    const int bhi = k >> 3;
    const int rb = k & 7;
    const int b = xcd + 8 * bhi;
    const int n0 = rb * 32;
    const int tid = threadIdx.x, w = tid >> 6, lane = tid & 63;
    const int g = lane >> 4, c = lane & 15;
    const int gsw = (g ^ ((c ^ (c >> 2)) & 3)) * 16;

    __shared__ __align__(16) unsigned char smem[49152];
    const char* vtbc = (const char*)vt_t + (size_t)b * 24 * 16384;

#define GSTAGE(ks, bsel)                                                        \
    {                                                                           \
        const char* vsl_ = vtbc + (size_t)(ks) * 16384;                         \
        _Pragma("unroll")                                                       \
        for (int q_ = 0; q_ < 4; q_++) {                                        \
            const int o_ = q_ * 4096 + tid * 16;                                \
            const int r_ = o_ >> 6;                                             \
            const int sj_ = ((o_ >> 4) & 3) ^ ((r_ ^ (r_ >> 2)) & 3);           \
            gl_lds16(vsl_ + r_ * 64 + sj_ * 16,                                 \
                     smem + (bsel) * 16384 + q_ * 4096 + w * 1024);             \
        }                                                                       \
    }

    f32x4 acc[4][2];
#pragma unroll
    for (int i = 0; i < 4; i++)
#pragma unroll
        for (int nb = 0; nb < 2; nb++) acc[i][nb] = {0.f, 0.f, 0.f, 0.f};

    GSTAGE(0, 0);
    GSTAGE(1, 1);
    asm volatile("s_waitcnt vmcnt(4)" ::: "memory");
    lite_barrier();

    for (int ks = 0; ks < 24; ks++) {
        if (ks < 22) GSTAGE(ks + 2, (ks + 2) % 3);
        const unsigned char* vb = smem + (ks % 3) * 16384;
        short8 af[2], bf[4];
#pragma unroll
        for (int nb = 0; nb < 2; nb++)
            af[nb] = *(const short8*)(vb + (n0 + nb * 16 + c) * 64 + gsw);
#pragma unroll
        for (int i = 0; i < 4; i++)
            bf[i] = *(const short8*)(vb + ((w + 4 * i) * 16 + c) * 64 + gsw);
#pragma unroll
        for (int i = 0; i < 4; i++)
#pragma unroll
            for (int nb = 0; nb < 2; nb++)
                acc[i][nb] = __builtin_amdgcn_mfma_f32_16x16x32_bf16(
                    af[nb], bf[i], acc[i][nb], 0, 0, 0);
        if (ks < 22) asm volatile("s_waitcnt vmcnt(4)" ::: "memory");
        else         asm volatile("s_waitcnt vmcnt(0)" ::: "memory");
        lite_barrier();
    }
#undef GSTAGE

    // write G_t[b][col>>5][row][col&31]
#pragma unroll
    for (int i = 0; i < 4; i++) {
        const int cw = w + 4 * i;
#pragma unroll
        for (int nb = 0; nb < 2; nb++)
#pragma unroll
            for (int r = 0; r < 4; r++)
                G_t[(((size_t)b * 8 + (cw >> 1)) * LP + n0 + nb * 16 + g * 4 + r) * 32 +
                    (cw & 1) * 16 + c] = __float2bfloat16(acc[i][nb][r]);
    }
}

// score: S = tf.vt^T, contiguous-tile staging (208 vt rows + 64 tf rows),
// double-buffer, counted vmcnt, light barriers. Softmax, num -> P_t + numq.
// Grid 1024, XCD-swizzled. (256,3). LDS 34816.
__global__ __launch_bounds__(256, 3) void score_kernel(
    const __hip_bfloat16* __restrict__ tf_t, const __hip_bfloat16* __restrict__ vt_t,
    const float* __restrict__ qinv, __hip_bfloat16* __restrict__ P_t,
    float* __restrict__ numq) {
    const int id = blockIdx.x;
    const int xcd = id & 7;
    const int kk = id >> 3;
    const int bhi = kk >> 4;
    const int nt = kk & 15;
    const int b = xcd + 8 * bhi;
    const int n0 = nt * 64;
    const int tid = threadIdx.x, w = tid >> 6, lane = tid & 63;
    const int g = lane >> 4, c = lane & 15;
    const int gsw = (g ^ ((c ^ (c >> 2)) & 3)) * 16;

    __shared__ __align__(16) unsigned char smem[34816];
    float* mx = (float*)smem;
    float* sm = mx + 256;
    float* nm = sm + 256;

    const char* vtbc = (const char*)vt_t + (size_t)b * 24 * 16384;
    const char* tfc = (const char*)tf_t;

#define SSTAGE(ks, bsel)                                                        \
    {                                                                           \
        const char* vsl_ = vtbc + (size_t)(ks) * 16384;                         \
        const char* tsl_ = tfc + (size_t)(ks) * 65536 + (size_t)n0 * 64;        \
        _Pragma("unroll")                                                       \
        for (int q_ = 0; q_ < 3; q_++) {                                        \
            const int o_ = q_ * 4096 + tid * 16;                                \
            const int r_ = o_ >> 6;                                             \
            const int sj_ = ((o_ >> 4) & 3) ^ ((r_ ^ (r_ >> 2)) & 3);           \
            gl_lds16(vsl_ + r_ * 64 + sj_ * 16,                                 \
                     smem + (bsel) * 13312 + q_ * 4096 + w * 1024);             \
        }                                                                       \
        if (lane < 16) {                                                        \
            const int o_ = 12288 + (w * 16 + lane) * 16;                        \
            const int r_ = o_ >> 6;                                             \
            const int sj_ = ((o_ >> 4) & 3) ^ ((r_ ^ (r_ >> 2)) & 3);           \
            gl_lds16(vsl_ + r_ * 64 + sj_ * 16,                                 \
                     smem + (bsel) * 13312 + 12288 + w * 256);                  \
        }                                                                       \
        {                                                                       \
            const int o_ = tid * 16;                                            \
            const int r_ = o_ >> 6;                                             \
            const int sj_ = ((o_ >> 4) & 3) ^ ((r_ ^ (r_ >> 2)) & 3);           \
            gl_lds16(tsl_ + r_ * 64 + sj_ * 16,                                 \
                     smem + 26624 + (bsel) * 4096 + w * 1024);                  \
        }                                                                       \
    }

    f32x4 acc[4][4];
#pragma unroll
    for (int i = 0; i < 4; i++)
#pragma unroll
        for (int nb = 0; nb < 4; nb++) acc[i][nb] = {0.f, 0.f, 0.f, 0.f};

    SSTAGE(0, 0);
    SSTAGE(1, 1);
    asm volatile("s_waitcnt vmcnt(5)" ::: "memory");
    lite_barrier();

    for (int ks = 0; ks < 24; ks++) {
        const unsigned char* vb = smem + (ks & 1) * 13312;
        const unsigned char* tb = smem + 26624 + (ks & 1) * 4096;
        short8 af[4];
#pragma unroll
        for (int nb = 0; nb < 4; nb++)
            af[nb] = *(const short8*)(tb + (nb * 16 + c) * 64 + gsw);
#pragma unroll
        for (int i = 0; i < 4; i++) {
            const int lb = w + 4 * i;
            if (lb < LBV) {
                short8 bfv = *(const short8*)(vb + (lb * 16 + c) * 64 + gsw);
#pragma unroll
                for (int nb = 0; nb < 4; nb++)
                    acc[i][nb] = __builtin_amdgcn_mfma_f32_16x16x32_bf16(
                        af[nb], bfv, acc[i][nb], 0, 0, 0);
            }
        }
        lite_barrier();
        if (ks < 22) {
            SSTAGE(ks + 2, ks & 1);
            asm volatile("s_waitcnt vmcnt(5)" ::: "memory");
        } else {
            asm volatile("s_waitcnt vmcnt(0)" ::: "memory");
        }
        lite_barrier();
    }
#undef SSTAGE

    // ---- softmax over l ----
    const float inv_sqrtD = 0.0360843918f;
    float mp[4][4];
#pragma unroll
    for (int nb = 0; nb < 4; nb++)
#pragma unroll
        for (int r = 0; r < 4; r++) mp[nb][r] = -1e30f;
#pragma unroll
    for (int i = 0; i < 4; i++) {
        const int l = (w + 4 * i) * 16 + c;
        if (l < LL) {
#pragma unroll
            for (int nb = 0; nb < 4; nb++)
#pragma unroll
                for (int r = 0; r < 4; r++) mp[nb][r] = fmaxf(mp[nb][r], acc[i][nb][r]);
        }
    }
#pragma unroll
    for (int nb = 0; nb < 4; nb++)
#pragma unroll
        for (int r = 0; r < 4; r++) mp[nb][r] = grpMax(mp[nb][r]);
    if (c == 0) {
#pragma unroll
        for (int nb = 0; nb < 4; nb++)
#pragma unroll
            for (int r = 0; r < 4; r++) mx[(nb * 16 + g * 4 + r) * 4 + w] = mp[nb][r];
    }
    __syncthreads();
    float mf[4][4];
#pragma unroll
    for (int nb = 0; nb < 4; nb++)
#pragma unroll
        for (int r = 0; r < 4; r++) {
            const int row = nb * 16 + g * 4 + r;
            mf[nb][r] = fmaxf(fmaxf(mx[row * 4 + 0], mx[row * 4 + 1]),
                              fmaxf(mx[row * 4 + 2], mx[row * 4 + 3]));
        }

    float sp[4][4], np[4][4];
#pragma unroll
    for (int nb = 0; nb < 4; nb++)
#pragma unroll
        for (int r = 0; r < 4; r++) { sp[nb][r] = 0.f; np[nb][r] = 0.f; }
#pragma unroll
    for (int i = 0; i < 4; i++) {
        const int l = (w + 4 * i) * 16 + c;
#pragma unroll
        for (int nb = 0; nb < 4; nb++)
#pragma unroll
            for (int r = 0; r < 4; r++) {
                const float raw = acc[i][nb][r];
                const float p = (l < LL) ? __expf((raw - mf[nb][r]) * inv_sqrtD) : 0.f;
                acc[i][nb][r] = p;
                sp[nb][r] += p;
                np[nb][r] += p * raw;
            }
    }
#pragma unroll
    for (int nb = 0; nb < 4; nb++)
#pragma unroll
        for (int r = 0; r < 4; r++) { sp[nb][r] = grpSum(sp[nb][r]); np[nb][r] = grpSum(np[nb][r]); }
    if (c == 0) {
#pragma unroll
        for (int nb = 0; nb < 4; nb++)
#pragma unroll
            for (int r = 0; r < 4; r++) {
                const int row = nb * 16 + g * 4 + r;
                sm[row * 4 + w] = sp[nb][r];
                nm[row * 4 + w] = np[nb][r];
            }
    }
    __syncthreads();

    float invs[4][4];
#pragma unroll
    for (int nb = 0; nb < 4; nb++)
#pragma unroll
        for (int r = 0; r < 4; r++) {
            const int row = nb * 16 + g * 4 + r;
            const float ssum = sm[row * 4 + 0] + sm[row * 4 + 1] + sm[row * 4 + 2] + sm[row * 4 + 3];
            invs[nb][r] = 1.f / ssum;
        }

    // P write into P_t[b][l>>5][n][l&31] (pad l-blocks write zeros)
#pragma unroll
    for (int i = 0; i < 4; i++) {
        const int lb = w + 4 * i;
#pragma unroll
        for (int nb = 0; nb < 4; nb++)
#pragma unroll
            for (int r = 0; r < 4; r++)
                P_t[(((size_t)b * 8 + (lb >> 1)) * NN + n0 + nb * 16 + g * 4 + r) * 32 +
                    (lb & 1) * 16 + c] = __float2bfloat16(acc[i][nb][r] * invs[nb][r]);
    }

    if (tid < 64) {
        const int row = tid;
        const int n = n0 + row;
        const float ssum = sm[row * 4 + 0] + sm[row * 4 + 1] + sm[row * 4 + 2] + sm[row * 4 + 3];
        const float nsum = nm[row * 4 + 0] + nm[row * 4 + 1] + nm[row * 4 + 2] + nm[row * 4 + 3];
        numq[(size_t)n * BB + b] = (nsum / ssum) * qinv[n];
    }
}

// den: T = P.G (contiguous tiles, double-buffer, counted vmcnt, 7 K-steps),
// den = sum P*T, logits. Grid 1024, XCD-swizzled. (256,3). LDS 34816.
__global__ __launch_bounds__(256, 3) void den_kernel(
    const __hip_bfloat16* __restrict__ P_t, const __hip_bfloat16* __restrict__ G_t,
    const float* __restrict__ numq, float* __restrict__ logits) {
    const int id = blockIdx.x;
    const int xcd = id & 7;
    const int kk = id >> 3;
    const int bhi = kk >> 4;
    const int nt = kk & 15;
    const int b = xcd + 8 * bhi;
    const int n0 = nt * 64;
    const int tid = threadIdx.x, w = tid >> 6, lane = tid & 63;
    const int g = lane >> 4, c = lane & 15;
    const int gsw = (g ^ ((c ^ (c >> 2)) & 3)) * 16;

    __shared__ __align__(16) unsigned char smem[34816];
    float* mx = (float*)smem;

    const char* Gbc = (const char*)G_t + (size_t)b * 8 * 16384;
    const char* Pbc = (const char*)P_t + (size_t)b * 8 * 65536;

#define DSTAGE(ks, bsel)                                                        \
    {                                                                           \
        const char* vsl_ = Gbc + (size_t)(ks) * 16384;                          \
        const char* psl_ = Pbc + (size_t)(ks) * 65536 + (size_t)n0 * 64;        \
        _Pragma("unroll")                                                       \
        for (int q_ = 0; q_ < 3; q_++) {                                        \
            const int o_ = q_ * 4096 + tid * 16;                                \
            const int r_ = o_ >> 6;                                             \
            const int sj_ = ((o_ >> 4) & 3) ^ ((r_ ^ (r_ >> 2)) & 3);           \
            gl_lds16(vsl_ + r_ * 64 + sj_ * 16,                                 \
                     smem + (bsel) * 13312 + q_ * 4096 + w * 1024);             \
        }                                                                       \
        if (lane < 16) {                                                        \
            const int o_ = 12288 + (w * 16 + lane) * 16;                        \
            const int r_ = o_ >> 6;                                             \
            const int sj_ = ((o_ >> 4) & 3) ^ ((r_ ^ (r_ >> 2)) & 3);           \
            gl_lds16(vsl_ + r_ * 64 + sj_ * 16,                                 \
                     smem + (bsel) * 13312 + 12288 + w * 256);                  \
        }                                                                       \
        {                                                                       \
            const int o_ = tid * 16;                                            \
            const int r_ = o_ >> 6;                                             \
            const int sj_ = ((o_ >> 4) & 3) ^ ((r_ ^ (r_ >> 2)) & 3);           \
            gl_lds16(psl_ + r_ * 64 + sj_ * 16,                                 \
                     smem + 26624 + (bsel) * 4096 + w * 1024);                  \
        }                                                                       \
    }

    f32x4 acc[4][4];
#pragma unroll
    for (int i = 0; i < 4; i++)
#pragma unroll
        for (int nb = 0; nb < 4; nb++) acc[i][nb] = {0.f, 0.f, 0.f, 0.f};

    DSTAGE(0, 0);
    DSTAGE(1, 1);
    asm volatile("s_waitcnt vmcnt(5)" ::: "memory");
    lite_barrier();

    for (int ks = 0; ks < 7; ks++) {
        const unsigned char* vb = smem + (ks & 1) * 13312;
        const unsigned char* tb = smem + 26624 + (ks & 1) * 4096;
        short8 af[4];
#pragma unroll
        for (int nb = 0; nb < 4; nb++)
            af[nb] = *(const short8*)(tb + (nb * 16 + c) * 64 + gsw);
#pragma unroll
        for (int i = 0; i < 4; i++) {
            const int lb = w + 4 * i;
            if (lb < LBV) {
                short8 bfv = *(const short8*)(vb + (lb * 16 + c) * 64 + gsw);
#pragma unroll
                for (int nb = 0; nb < 4; nb++)
                    acc[i][nb] = __builtin_amdgcn_mfma_f32_16x16x32_bf16(
                        af[nb], bfv, acc[i][nb], 0, 0, 0);
            }
        }
        lite_barrier();
        if (ks < 5) {
            DSTAGE(ks + 2, ks & 1);
            asm volatile("s_waitcnt vmcnt(5)" ::: "memory");
        } else {
            asm volatile("s_waitcnt vmcnt(0)" ::: "memory");
        }
        lite_barrier();
    }
#undef DSTAGE

    // den = sum over valid cols of P * T (P re-read from L2-hot P_t)
    const short* Pg = (const short*)P_t;
    float den[4][4];
#pragma unroll
    for (int nb = 0; nb < 4; nb++)
#pragma unroll
        for (int r = 0; r < 4; r++) den[nb][r] = 0.f;
#pragma unroll
    for (int i = 0; i < 4; i++) {
        const int lb = w + 4 * i;
        if (lb < LBV) {
#pragma unroll
            for (int nb = 0; nb < 4; nb++)
#pragma unroll
                for (int r = 0; r < 4; r++) {
                    const size_t pa = (((size_t)b * 8 + (lb >> 1)) * NN + n0 + nb * 16 + g * 4 + r) * 32 +
                                      (lb & 1) * 16 + c;
                    den[nb][r] += bf2f((unsigned short)Pg[pa]) * acc[i][nb][r];
                }
        }
    }

#pragma unroll
    for (int nb = 0; nb < 4; nb++)
#pragma unroll
        for (int r = 0; r < 4; r++) den[nb][r] = grpSum(den[nb][r]);
    __syncthreads();
    if (c == 0) {
#pragma unroll
        for (int nb = 0; nb < 4; nb++)
#pragma unroll
            for (int r = 0; r < 4; r++) mx[(nb * 16 + g * 4 + r) * 4 + w] = den[nb][r];
    }
    __syncthreads();
    if (tid < 64) {
        const int row = tid;
        const int n = n0 + row;
        const float dsum = mx[row * 4 + 0] + mx[row * 4 + 1] + mx[row * 4 + 2] + mx[row * 4 + 3];
        const float dn = fmaxf(sqrtf(fmaxf(dsum, 0.f)), NORM_EPS);
        logits[(size_t)n * BB + b] = numq[(size_t)n * BB + b] / dn;
    }
}

__global__ __launch_bounds__(64) void loss_row_kernel(
    const float* __restrict__ logits, const int* __restrict__ gm,
    const float* __restrict__ logtemp, float* __restrict__ scaled,
    float* __restrict__ posv, float* __restrict__ rowloss) {
    const int n = blockIdx.x;
    const int b = threadIdx.x;
    const float invtemp = 1.f / expf(logtemp[0]);
    const float e = expf(logits[(size_t)n * BB + b] * invtemp);
    scaled[(size_t)n * BB + b] = e;
    const float sum = waveSum(e);
    const int g = gm[n];
    const float pos = __shfl(e, g, 64);
    if (b == 0) {
        posv[n] = pos;
        rowloss[n] = -logf(pos / (sum + EPS) + EPS);
    }
}

__global__ __launch_bounds__(256) void colsum_kernel(
    const float* __restrict__ scaled, const int* __restrict__ gm,
    float* __restrict__ colsum, float* __restrict__ poscol) {
    const int b = blockIdx.x;
    const int tid = threadIdx.x;
    float s = 0.f, p = 0.f;
    for (int n = tid; n < NN; n += 256) {
        const float e = scaled[(size_t)n * BB + b];
        s += e;
        if (gm[n] == b) p += e;
    }
    s = waveSum(s); p = waveSum(p);
    __shared__ float red[8];
    const int w = tid >> 6;
    if ((tid & 63) == 0) { red[w] = s; red[4 + w] = p; }
    __syncthreads();
    if (tid == 0) {
        colsum[b] = red[0] + red[1] + red[2] + red[3];
        poscol[b] = red[4] + red[5] + red[6] + red[7];
    }
}

__global__ __launch_bounds__(1024) void final_kernel(
    const float* __restrict__ posv, const float* __restrict__ rowloss,
    const float* __restrict__ colsum, const float* __restrict__ poscol,
    const int* __restrict__ gm, float* __restrict__ out) {
    const int n = threadIdx.x;
    const int g = gm[n];
    const float pos = posv[n];
    const float sum_neg = colsum[g] - poscol[g];
    const float cl = -logf(pos / (pos + sum_neg + EPS) + EPS);
    float v = rowloss[n] + cl;
    v = waveSum(v);
    __shared__ float red[16];
    if ((n & 63) == 0) red[n >> 6] = v;
    __syncthreads();
    if (n == 0) {
        float s = 0.f;
#pragma unroll
        for (int i = 0; i < 16; i++) s += red[i];
        out[0] = s / (2.f * NN);
    }
}

extern "C" void kernel_launch(void* const* d_in, const int* in_sizes, int n_in,
                              void* d_out, int out_size, void* d_ws, size_t ws_size,
                              hipStream_t stream) {
    const float* text = (const float*)d_in[0];
    const float* vis = (const float*)d_in[1];
    const int* gm = (const int*)d_in[2];
    const float* gamma = (const float*)d_in[3];
    const float* beta = (const float*)d_in[4];
    const float* logtemp = (const float*)d_in[5];
    float* out = (float*)d_out;

    char* w = (char*)d_ws;
    __hip_bfloat16* tf_t = (__hip_bfloat16*)w;  w += (size_t)24 * NN * 32 * 2;        // 1.57 MB
    __hip_bfloat16* vt_t = (__hip_bfloat16*)w;  w += (size_t)BB * 24 * LP * 32 * 2;   // 25.2 MB
    __hip_bfloat16* G_t  = (__hip_bfloat16*)w;  w += (size_t)BB * 8 * LP * 32 * 2;    // 8.4 MB
    __hip_bfloat16* P_t  = (__hip_bfloat16*)w;  w += (size_t)BB * 8 * NN * 32 * 2;    // 33.6 MB
    float* qinv    = (float*)w;  w += (size_t)NN * 4;
    float* numq    = (float*)w;  w += (size_t)NN * BB * 4;
    float* logits  = (float*)w;  w += (size_t)NN * BB * 4;
    float* scaled  = (float*)w;  w += (size_t)NN * BB * 4;
    float* posv    = (float*)w;  w += (size_t)NN * 4;
    float* rowloss = (float*)w;  w += (size_t)NN * 4;
    float* colsum  = (float*)w;  w += (size_t)BB * 4;
    float* poscol  = (float*)w;  w += (size_t)BB * 4;

    ln_kernel<<<NN, 256, 0, stream>>>(text, tf_t, gamma, beta, qinv);
    ln_vis_kernel<<<BB * LP, 256, 0, stream>>>(vis, vt_t, gamma, beta);

    score_kernel<<<1024, 256, 0, stream>>>(tf_t, vt_t, qinv, P_t, numq);
    gram_kernel<<<512, 256, 0, stream>>>(vt_t, G_t);
    den_kernel<<<1024, 256, 0, stream>>>(P_t, G_t, numq, logits);

    loss_row_kernel<<<NN, 64, 0, stream>>>(logits, gm, logtemp, scaled, posv, rowloss);
    colsum_kernel<<<BB, 256, 0, stream>>>(scaled, gm, colsum, poscol);
    final_kernel<<<1, 1024, 0, stream>>>(posv, rowloss, colsum, poscol, gm, out);
}

// Round 20
// 109.272 us; speedup vs baseline: 1.0671x; 1.0341x over previous
//
#include <hip/hip_runtime.h>
#include <hip/hip_bf16.h>
#include <math.h>

#define NN 1024
#define BB 64
#define LL 197
#define LP 256
#define LBV 13        // valid l-blocks (l < 208 covers LL=197)
#define DD 768

typedef __attribute__((ext_vector_type(8))) short short8;
typedef __attribute__((ext_vector_type(4))) float f32x4;

constexpr float LN_EPS = 1e-5f;
constexpr float NORM_EPS = 1e-12f;
constexpr float EPS = 1e-8f;

__device__ __forceinline__ float waveSum(float v) {
#pragma unroll
    for (int m = 32; m >= 1; m >>= 1) v += __shfl_xor(v, m, 64);
    return v;
}
__device__ __forceinline__ float grpSum(float v) {
#pragma unroll
    for (int m = 8; m >= 1; m >>= 1) v += __shfl_xor(v, m, 64);
    return v;
}
__device__ __forceinline__ float grpMax(float v) {
#pragma unroll
    for (int m = 8; m >= 1; m >>= 1) v = fmaxf(v, __shfl_xor(v, m, 64));
    return v;
}

__device__ __forceinline__ float bf2f(unsigned short u) {
    unsigned int x = ((unsigned int)u) << 16;
    return reinterpret_cast<float&>(x);
}

__device__ __forceinline__ void gl_lds16(const void* g, void* l) {
    __builtin_amdgcn_global_load_lds(
        (const __attribute__((address_space(1))) unsigned int*)g,
        (__attribute__((address_space(3))) unsigned int*)l, 16, 0, 0);
}

// Light barrier: memory-ordering only (no sched pins, no vmcnt(0) drain).
__device__ __forceinline__ void lite_barrier() {
    asm volatile("s_barrier" ::: "memory");
}

// Text LayerNorm -> bf16 K-tiled tf_t[24][NN][32] + qinv
__global__ __launch_bounds__(256) void ln_kernel(
    const float* __restrict__ x, __hip_bfloat16* __restrict__ y,
    const float* __restrict__ gamma, const float* __restrict__ beta,
    float* __restrict__ qinv) {
    const int row = blockIdx.x;
    const int tid = threadIdx.x;
    const float* xr = x + (size_t)row * DD;

    float v[3];
    float s = 0.f, ss = 0.f;
#pragma unroll
    for (int c = 0; c < 3; c++) {
        float t = xr[tid + 256 * c];
        v[c] = t; s += t; ss += t * t;
    }
    __shared__ float red[8];
    s = waveSum(s); ss = waveSum(ss);
    const int w = tid >> 6;
    if ((tid & 63) == 0) { red[w] = s; red[4 + w] = ss; }
    __syncthreads();
    s = red[0] + red[1] + red[2] + red[3];
    ss = red[4] + red[5] + red[6] + red[7];
    const float mean = s * (1.f / DD);
    const float var = ss * (1.f / DD) - mean * mean;
    const float rs = rsqrtf(var + LN_EPS);

    float q = 0.f;
#pragma unroll
    for (int c = 0; c < 3; c++) {
        const int d = tid + 256 * c;
        float t = (v[c] - mean) * rs * gamma[d] + beta[d];
        __hip_bfloat16 hb = __float2bfloat16(t);
        y[((size_t)(d >> 5) * NN + row) * 32 + (d & 31)] = hb;
        float tb = __bfloat162float(hb);
        q += tb * tb;
    }
    __syncthreads();
    q = waveSum(q);
    if ((tid & 63) == 0) red[w] = q;
    __syncthreads();
    if (tid == 0) {
        float n2 = red[0] + red[1] + red[2] + red[3];
        qinv[row] = 1.f / fmaxf(sqrtf(n2), NORM_EPS);
    }
}

// Vision LayerNorm -> bf16 K-tiled vt_t[B][24][LP][32]; pad rows zero.
__global__ __launch_bounds__(256) void ln_vis_kernel(
    const float* __restrict__ x, __hip_bfloat16* __restrict__ y,
    const float* __restrict__ gamma, const float* __restrict__ beta) {
    const int id = blockIdx.x;           // 0..BB*LP-1
    const int xcd = id & 7;
    const int k = id >> 3;
    const int bhi = k >> 8;
    const int l = k & 255;
    const int b = xcd + 8 * bhi;
    const int tid = threadIdx.x;
    if (l >= LL) {
#pragma unroll
        for (int c = 0; c < 3; c++) {
            const int d = tid + 256 * c;
            y[(((size_t)b * 24 + (d >> 5)) * LP + l) * 32 + (d & 31)] = __float2bfloat16(0.f);
        }
        return;
    }
    const float* xr = x + ((size_t)b * LL + l) * DD;

    float v[3];
    float s = 0.f, ss = 0.f;
#pragma unroll
    for (int c = 0; c < 3; c++) {
        float t = xr[tid + 256 * c];
        v[c] = t; s += t; ss += t * t;
    }
    __shared__ float red[8];
    s = waveSum(s); ss = waveSum(ss);
    const int w = tid >> 6;
    if ((tid & 63) == 0) { red[w] = s; red[4 + w] = ss; }
    __syncthreads();
    s = red[0] + red[1] + red[2] + red[3];
    ss = red[4] + red[5] + red[6] + red[7];
    const float mean = s * (1.f / DD);
    const float var = ss * (1.f / DD) - mean * mean;
    const float rs = rsqrtf(var + LN_EPS);
#pragma unroll
    for (int c = 0; c < 3; c++) {
        const int d = tid + 256 * c;
        y[(((size_t)b * 24 + (d >> 5)) * LP + l) * 32 + (d & 31)] =
            __float2bfloat16((v[c] - mean) * rs * gamma[d] + beta[d]);
    }
}

// Gram: G_t[b][8][LP][32] = vt.vt^T, contiguous-tile staging, triple-buffer,
// counted vmcnt, 1 light barrier/iter. Grid 512, XCD-swizzled. LDS 49152.
__global__ __launch_bounds__(256, 2) void gram_kernel(
    const __hip_bfloat16* __restrict__ vt_t, __hip_bfloat16* __restrict__ G_t) {
    const int id = blockIdx.x;           // 0..511
    const int xcd = id & 7;
    const int k = id >> 3;
    const int bhi = k >> 3;
    const int rb = k & 7;
    const int b = xcd + 8 * bhi;
    const int n0 = rb * 32;
    const int tid = threadIdx.x, w = tid >> 6, lane = tid & 63;
    const int g = lane >> 4, c = lane & 15;
    const int gsw = (g ^ ((c ^ (c >> 2)) & 3)) * 16;

    __shared__ __align__(16) unsigned char smem[49152];
    const char* vtbc = (const char*)vt_t + (size_t)b * 24 * 16384;

#define GSTAGE(ks, bsel)                                                        \
    {                                                                           \
        const char* vsl_ = vtbc + (size_t)(ks) * 16384;                         \
        _Pragma("unroll")                                                       \
        for (int q_ = 0; q_ < 4; q_++) {                                        \
            const int o_ = q_ * 4096 + tid * 16;                                \
            const int r_ = o_ >> 6;                                             \
            const int sj_ = ((o_ >> 4) & 3) ^ ((r_ ^ (r_ >> 2)) & 3);           \
            gl_lds16(vsl_ + r_ * 64 + sj_ * 16,                                 \
                     smem + (bsel) * 16384 + q_ * 4096 + w * 1024);             \
        }                                                                       \
    }

    f32x4 acc[4][2];
#pragma unroll
    for (int i = 0; i < 4; i++)
#pragma unroll
        for (int nb = 0; nb < 2; nb++) acc[i][nb] = {0.f, 0.f, 0.f, 0.f};

    GSTAGE(0, 0);
    GSTAGE(1, 1);
    asm volatile("s_waitcnt vmcnt(4)" ::: "memory");
    lite_barrier();

    for (int ks = 0; ks < 24; ks++) {
        if (ks < 22) GSTAGE(ks + 2, (ks + 2) % 3);
        const unsigned char* vb = smem + (ks % 3) * 16384;
        short8 af[2], bf[4];
#pragma unroll
        for (int nb = 0; nb < 2; nb++)
            af[nb] = *(const short8*)(vb + (n0 + nb * 16 + c) * 64 + gsw);
#pragma unroll
        for (int i = 0; i < 4; i++)
            bf[i] = *(const short8*)(vb + ((w + 4 * i) * 16 + c) * 64 + gsw);
#pragma unroll
        for (int i = 0; i < 4; i++)
#pragma unroll
            for (int nb = 0; nb < 2; nb++)
                acc[i][nb] = __builtin_amdgcn_mfma_f32_16x16x32_bf16(
                    af[nb], bf[i], acc[i][nb], 0, 0, 0);
        if (ks < 22) asm volatile("s_waitcnt vmcnt(4)" ::: "memory");
        else         asm volatile("s_waitcnt vmcnt(0)" ::: "memory");
        lite_barrier();
    }
#undef GSTAGE

#pragma unroll
    for (int i = 0; i < 4; i++) {
        const int cw = w + 4 * i;
#pragma unroll
        for (int nb = 0; nb < 2; nb++)
#pragma unroll
            for (int r = 0; r < 4; r++)
                G_t[(((size_t)b * 8 + (cw >> 1)) * LP + n0 + nb * 16 + g * 4 + r) * 32 +
                    (cw & 1) * 16 + c] = __float2bfloat16(acc[i][nb][r]);
    }
}

// score: BM=128. 512 thr = 8 waves (wn = w>>2 n-half, wl = w&3 l-group).
// Stages full 256-row vt slice (16KB, 2 uniform rounds) + 128-row tf slice
// (8KB, 1 round) -> 3 gl_lds/thread/tile, vmcnt(3) exact. Double-buffer,
// light barriers. Softmax, num -> P_t + numq. Grid 512, XCD-swizzled.
__global__ __launch_bounds__(512, 2) void score_kernel(
    const __hip_bfloat16* __restrict__ tf_t, const __hip_bfloat16* __restrict__ vt_t,
    const float* __restrict__ qinv, __hip_bfloat16* __restrict__ P_t,
    float* __restrict__ numq) {
    const int id = blockIdx.x;           // 0..511
    const int xcd = id & 7;
    const int kk = id >> 3;              // 0..63
    const int bhi = kk >> 3;             // 0..7
    const int nt = kk & 7;               // 0..7
    const int b = xcd + 8 * bhi;
    const int n0 = nt * 128;
    const int tid = threadIdx.x, w = tid >> 6, lane = tid & 63;
    const int wn = w >> 2, wl = w & 3;
    const int g = lane >> 4, c = lane & 15;
    const int gsw = (g ^ ((c ^ (c >> 2)) & 3)) * 16;

    __shared__ __align__(16) unsigned char smem[49152];
    float* mx = (float*)smem;            // [128][4] overlay (post-stage1)
    float* sm = mx + 512;
    float* nm = sm + 512;

    const char* vtbc = (const char*)vt_t + (size_t)b * 24 * 16384;
    const char* tfc = (const char*)tf_t;

// vbuf[bsel] @ bsel*16384 (32KB, 256 rows x 64B), tbuf[bsel] @ 32768+bsel*8192
#define SSTAGE(ks, bsel)                                                        \
    {                                                                           \
        const char* vsl_ = vtbc + (size_t)(ks) * 16384;                         \
        const char* tsl_ = tfc + (size_t)(ks) * 65536 + (size_t)n0 * 64;        \
        _Pragma("unroll")                                                       \
        for (int q_ = 0; q_ < 2; q_++) {                                        \
            const int o_ = q_ * 8192 + tid * 16;                                \
            const int r_ = o_ >> 6;                                             \
            const int sj_ = ((o_ >> 4) & 3) ^ ((r_ ^ (r_ >> 2)) & 3);           \
            gl_lds16(vsl_ + r_ * 64 + sj_ * 16,                                 \
                     smem + (bsel) * 16384 + q_ * 8192 + w * 1024);             \
        }                                                                       \
        {                                                                       \
            const int o_ = tid * 16;                                            \
            const int r_ = o_ >> 6;                                             \
            const int sj_ = ((o_ >> 4) & 3) ^ ((r_ ^ (r_ >> 2)) & 3);           \
            gl_lds16(tsl_ + r_ * 64 + sj_ * 16,                                 \
                     smem + 32768 + (bsel) * 8192 + w * 1024);                  \
        }                                                                       \
    }

    f32x4 acc[4][4];  // [i = lb slot][nb]
#pragma unroll
    for (int i = 0; i < 4; i++)
#pragma unroll
        for (int nb = 0; nb < 4; nb++) acc[i][nb] = {0.f, 0.f, 0.f, 0.f};

    SSTAGE(0, 0);
    SSTAGE(1, 1);
    asm volatile("s_waitcnt vmcnt(3)" ::: "memory");
    lite_barrier();

    for (int ks = 0; ks < 24; ks++) {
        const unsigned char* vb = smem + (ks & 1) * 16384;
        const unsigned char* tb = smem + 32768 + (ks & 1) * 8192;
        short8 af[4];
#pragma unroll
        for (int nb = 0; nb < 4; nb++)
            af[nb] = *(const short8*)(tb + (wn * 64 + nb * 16 + c) * 64 + gsw);
#pragma unroll
        for (int i = 0; i < 4; i++) {
            const int lb = wl + 4 * i;
            if (lb < LBV) {
                short8 bfv = *(const short8*)(vb + (lb * 16 + c) * 64 + gsw);
#pragma unroll
                for (int nb = 0; nb < 4; nb++)
                    acc[i][nb] = __builtin_amdgcn_mfma_f32_16x16x32_bf16(
                        af[nb], bfv, acc[i][nb], 0, 0, 0);
            }
        }
        lite_barrier();
        if (ks < 22) {
            SSTAGE(ks + 2, ks & 1);
            asm volatile("s_waitcnt vmcnt(3)" ::: "memory");
        } else {
            asm volatile("s_waitcnt vmcnt(0)" ::: "memory");
        }
        lite_barrier();
    }
#undef SSTAGE

    // ---- softmax over l (wl groups hold disjoint l-columns; wn splits rows) ----
    const float inv_sqrtD = 0.0360843918f;
    float mp[4][4];
#pragma unroll
    for (int nb = 0; nb < 4; nb++)
#pragma unroll
        for (int r = 0; r < 4; r++) mp[nb][r] = -1e30f;
#pragma unroll
    for (int i = 0; i < 4; i++) {
        const int l = (wl + 4 * i) * 16 + c;
        if (l < LL) {
#pragma unroll
            for (int nb = 0; nb < 4; nb++)
#pragma unroll
                for (int r = 0; r < 4; r++) mp[nb][r] = fmaxf(mp[nb][r], acc[i][nb][r]);
        }
    }
#pragma unroll
    for (int nb = 0; nb < 4; nb++)
#pragma unroll
        for (int r = 0; r < 4; r++) mp[nb][r] = grpMax(mp[nb][r]);
    if (c == 0) {
#pragma unroll
        for (int nb = 0; nb < 4; nb++)
#pragma unroll
            for (int r = 0; r < 4; r++)
                mx[(wn * 64 + nb * 16 + g * 4 + r) * 4 + wl] = mp[nb][r];
    }
    __syncthreads();
    float mf[4][4];
#pragma unroll
    for (int nb = 0; nb < 4; nb++)
#pragma unroll
        for (int r = 0; r < 4; r++) {
            const int row = wn * 64 + nb * 16 + g * 4 + r;
            mf[nb][r] = fmaxf(fmaxf(mx[row * 4 + 0], mx[row * 4 + 1]),
                              fmaxf(mx[row * 4 + 2], mx[row * 4 + 3]));
        }

    float sp[4][4], np[4][4];
#pragma unroll
    for (int nb = 0; nb < 4; nb++)
#pragma unroll
        for (int r = 0; r < 4; r++) { sp[nb][r] = 0.f; np[nb][r] = 0.f; }
#pragma unroll
    for (int i = 0; i < 4; i++) {
        const int l = (wl + 4 * i) * 16 + c;
#pragma unroll
        for (int nb = 0; nb < 4; nb++)
#pragma unroll
            for (int r = 0; r < 4; r++) {
                const float raw = acc[i][nb][r];
                const float p = (l < LL) ? __expf((raw - mf[nb][r]) * inv_sqrtD) : 0.f;
                acc[i][nb][r] = p;
                sp[nb][r] += p;
                np[nb][r] += p * raw;
            }
    }
#pragma unroll
    for (int nb = 0; nb < 4; nb++)
#pragma unroll
        for (int r = 0; r < 4; r++) { sp[nb][r] = grpSum(sp[nb][r]); np[nb][r] = grpSum(np[nb][r]); }
    if (c == 0) {
#pragma unroll
        for (int nb = 0; nb < 4; nb++)
#pragma unroll
            for (int r = 0; r < 4; r++) {
                const int row = wn * 64 + nb * 16 + g * 4 + r;
                sm[row * 4 + wl] = sp[nb][r];
                nm[row * 4 + wl] = np[nb][r];
            }
    }
    __syncthreads();

    float invs[4][4];
#pragma unroll
    for (int nb = 0; nb < 4; nb++)
#pragma unroll
        for (int r = 0; r < 4; r++) {
            const int row = wn * 64 + nb * 16 + g * 4 + r;
            const float ssum = sm[row * 4 + 0] + sm[row * 4 + 1] + sm[row * 4 + 2] + sm[row * 4 + 3];
            invs[nb][r] = 1.f / ssum;
        }

    // P write into P_t[b][l>>5][n][l&31] (pad l-blocks write zeros)
#pragma unroll
    for (int i = 0; i < 4; i++) {
        const int lb = wl + 4 * i;
#pragma unroll
        for (int nb = 0; nb < 4; nb++)
#pragma unroll
            for (int r = 0; r < 4; r++)
                P_t[(((size_t)b * 8 + (lb >> 1)) * NN + n0 + wn * 64 + nb * 16 + g * 4 + r) * 32 +
                    (lb & 1) * 16 + c] = __float2bfloat16(acc[i][nb][r] * invs[nb][r]);
    }

    if (tid < 128) {
        const int row = tid;
        const int n = n0 + row;
        const float ssum = sm[row * 4 + 0] + sm[row * 4 + 1] + sm[row * 4 + 2] + sm[row * 4 + 3];
        const float nsum = nm[row * 4 + 0] + nm[row * 4 + 1] + nm[row * 4 + 2] + nm[row * 4 + 3];
        numq[(size_t)n * BB + b] = (nsum / ssum) * qinv[n];
    }
}

// den: T = P.G (contiguous tiles, double-buffer, counted vmcnt, 7 K-steps),
// den = sum P*T, logits. Grid 1024, XCD-swizzled. (256,3). LDS 34816.
__global__ __launch_bounds__(256, 3) void den_kernel(
    const __hip_bfloat16* __restrict__ P_t, const __hip_bfloat16* __restrict__ G_t,
    const float* __restrict__ numq, float* __restrict__ logits) {
    const int id = blockIdx.x;
    const int xcd = id & 7;
    const int kk = id >> 3;
    const int bhi = kk >> 4;
    const int nt = kk & 15;
    const int b = xcd + 8 * bhi;
    const int n0 = nt * 64;
    const int tid = threadIdx.x, w = tid >> 6, lane = tid & 63;
    const int g = lane >> 4, c = lane & 15;
    const int gsw = (g ^ ((c ^ (c >> 2)) & 3)) * 16;

    __shared__ __align__(16) unsigned char smem[34816];
    float* mx = (float*)smem;

    const char* Gbc = (const char*)G_t + (size_t)b * 8 * 16384;
    const char* Pbc = (const char*)P_t + (size_t)b * 8 * 65536;

#define DSTAGE(ks, bsel)                                                        \
    {                                                                           \
        const char* vsl_ = Gbc + (size_t)(ks) * 16384;                          \
        const char* psl_ = Pbc + (size_t)(ks) * 65536 + (size_t)n0 * 64;        \
        _Pragma("unroll")                                                       \
        for (int q_ = 0; q_ < 3; q_++) {                                        \
            const int o_ = q_ * 4096 + tid * 16;                                \
            const int r_ = o_ >> 6;                                             \
            const int sj_ = ((o_ >> 4) & 3) ^ ((r_ ^ (r_ >> 2)) & 3);           \
            gl_lds16(vsl_ + r_ * 64 + sj_ * 16,                                 \
                     smem + (bsel) * 13312 + q_ * 4096 + w * 1024);             \
        }                                                                       \
        if (lane < 16) {                                                        \
            const int o_ = 12288 + (w * 16 + lane) * 16;                        \
            const int r_ = o_ >> 6;                                             \
            const int sj_ = ((o_ >> 4) & 3) ^ ((r_ ^ (r_ >> 2)) & 3);           \
            gl_lds16(vsl_ + r_ * 64 + sj_ * 16,                                 \
                     smem + (bsel) * 13312 + 12288 + w * 256);                  \
        }                                                                       \
        {                                                                       \
            const int o_ = tid * 16;                                            \
            const int r_ = o_ >> 6;                                             \
            const int sj_ = ((o_ >> 4) & 3) ^ ((r_ ^ (r_ >> 2)) & 3);           \
            gl_lds16(psl_ + r_ * 64 + sj_ * 16,                                 \
                     smem + 26624 + (bsel) * 4096 + w * 1024);                  \
        }                                                                       \
    }

    f32x4 acc[4][4];
#pragma unroll
    for (int i = 0; i < 4; i++)
#pragma unroll
        for (int nb = 0; nb < 4; nb++) acc[i][nb] = {0.f, 0.f, 0.f, 0.f};

    DSTAGE(0, 0);
    DSTAGE(1, 1);
    asm volatile("s_waitcnt vmcnt(5)" ::: "memory");
    lite_barrier();

    for (int ks = 0; ks < 7; ks++) {
        const unsigned char* vb = smem + (ks & 1) * 13312;
        const unsigned char* tb = smem + 26624 + (ks & 1) * 4096;
        short8 af[4];
#pragma unroll
        for (int nb = 0; nb < 4; nb++)
            af[nb] = *(const short8*)(tb + (nb * 16 + c) * 64 + gsw);
#pragma unroll
        for (int i = 0; i < 4; i++) {
            const int lb = w + 4 * i;
            if (lb < LBV) {
                short8 bfv = *(const short8*)(vb + (lb * 16 + c) * 64 + gsw);
#pragma unroll
                for (int nb = 0; nb < 4; nb++)
                    acc[i][nb] = __builtin_amdgcn_mfma_f32_16x16x32_bf16(
                        af[nb], bfv, acc[i][nb], 0, 0, 0);
            }
        }
        lite_barrier();
        if (ks < 5) {
            DSTAGE(ks + 2, ks & 1);
            asm volatile("s_waitcnt vmcnt(5)" ::: "memory");
        } else {
            asm volatile("s_waitcnt vmcnt(0)" ::: "memory");
        }
        lite_barrier();
    }
#undef DSTAGE

    const short* Pg = (const short*)P_t;
    float den[4][4];
#pragma unroll
    for (int nb = 0; nb < 4; nb++)
#pragma unroll
        for (int r = 0; r < 4; r++) den[nb][r] = 0.f;
#pragma unroll
    for (int i = 0; i < 4; i++) {
        const int lb = w + 4 * i;
        if (lb < LBV) {
#pragma unroll
            for (int nb = 0; nb < 4; nb++)
#pragma unroll
                for (int r = 0; r < 4; r++) {
                    const size_t pa = (((size_t)b * 8 + (lb >> 1)) * NN + n0 + nb * 16 + g * 4 + r) * 32 +
                                      (lb & 1) * 16 + c;
                    den[nb][r] += bf2f((unsigned short)Pg[pa]) * acc[i][nb][r];
                }
        }
    }

#pragma unroll
    for (int nb = 0; nb < 4; nb++)
#pragma unroll
        for (int r = 0; r < 4; r++) den[nb][r] = grpSum(den[nb][r]);
    __syncthreads();
    if (c == 0) {
#pragma unroll
        for (int nb = 0; nb < 4; nb++)
#pragma unroll
            for (int r = 0; r < 4; r++) mx[(nb * 16 + g * 4 + r) * 4 + w] = den[nb][r];
    }
    __syncthreads();
    if (tid < 64) {
        const int row = tid;
        const int n = n0 + row;
        const float dsum = mx[row * 4 + 0] + mx[row * 4 + 1] + mx[row * 4 + 2] + mx[row * 4 + 3];
        const float dn = fmaxf(sqrtf(fmaxf(dsum, 0.f)), NORM_EPS);
        logits[(size_t)n * BB + b] = numq[(size_t)n * BB + b] / dn;
    }
}

__global__ __launch_bounds__(64) void loss_row_kernel(
    const float* __restrict__ logits, const int* __restrict__ gm,
    const float* __restrict__ logtemp, float* __restrict__ scaled,
    float* __restrict__ posv, float* __restrict__ rowloss) {
    const int n = blockIdx.x;
    const int b = threadIdx.x;
    const float invtemp = 1.f / expf(logtemp[0]);
    const float e = expf(logits[(size_t)n * BB + b] * invtemp);
    scaled[(size_t)n * BB + b] = e;
    const float sum = waveSum(e);
    const int g = gm[n];
    const float pos = __shfl(e, g, 64);
    if (b == 0) {
        posv[n] = pos;
        rowloss[n] = -logf(pos / (sum + EPS) + EPS);
    }
}

__global__ __launch_bounds__(256) void colsum_kernel(
    const float* __restrict__ scaled, const int* __restrict__ gm,
    float* __restrict__ colsum, float* __restrict__ poscol) {
    const int b = blockIdx.x;
    const int tid = threadIdx.x;
    float s = 0.f, p = 0.f;
    for (int n = tid; n < NN; n += 256) {
        const float e = scaled[(size_t)n * BB + b];
        s += e;
        if (gm[n] == b) p += e;
    }
    s = waveSum(s); p = waveSum(p);
    __shared__ float red[8];
    const int w = tid >> 6;
    if ((tid & 63) == 0) { red[w] = s; red[4 + w] = p; }
    __syncthreads();
    if (tid == 0) {
        colsum[b] = red[0] + red[1] + red[2] + red[3];
        poscol[b] = red[4] + red[5] + red[6] + red[7];
    }
}

__global__ __launch_bounds__(1024) void final_kernel(
    const float* __restrict__ posv, const float* __restrict__ rowloss,
    const float* __restrict__ colsum, const float* __restrict__ poscol,
    const int* __restrict__ gm, float* __restrict__ out) {
    const int n = threadIdx.x;
    const int g = gm[n];
    const float pos = posv[n];
    const float sum_neg = colsum[g] - poscol[g];
    const float cl = -logf(pos / (pos + sum_neg + EPS) + EPS);
    float v = rowloss[n] + cl;
    v = waveSum(v);
    __shared__ float red[16];
    if ((n & 63) == 0) red[n >> 6] = v;
    __syncthreads();
    if (n == 0) {
        float s = 0.f;
#pragma unroll
        for (int i = 0; i < 16; i++) s += red[i];
        out[0] = s / (2.f * NN);
    }
}

extern "C" void kernel_launch(void* const* d_in, const int* in_sizes, int n_in,
                              void* d_out, int out_size, void* d_ws, size_t ws_size,
                              hipStream_t stream) {
    const float* text = (const float*)d_in[0];
    const float* vis = (const float*)d_in[1];
    const int* gm = (const int*)d_in[2];
    const float* gamma = (const float*)d_in[3];
    const float* beta = (const float*)d_in[4];
    const float* logtemp = (const float*)d_in[5];
    float* out = (float*)d_out;

    char* w = (char*)d_ws;
    __hip_bfloat16* tf_t = (__hip_bfloat16*)w;  w += (size_t)24 * NN * 32 * 2;
    __hip_bfloat16* vt_t = (__hip_bfloat16*)w;  w += (size_t)BB * 24 * LP * 32 * 2;
    __hip_bfloat16* G_t  = (__hip_bfloat16*)w;  w += (size_t)BB * 8 * LP * 32 * 2;
    __hip_bfloat16* P_t  = (__hip_bfloat16*)w;  w += (size_t)BB * 8 * NN * 32 * 2;
    float* qinv    = (float*)w;  w += (size_t)NN * 4;
    float* numq    = (float*)w;  w += (size_t)NN * BB * 4;
    float* logits  = (float*)w;  w += (size_t)NN * BB * 4;
    float* scaled  = (float*)w;  w += (size_t)NN * BB * 4;
    float* posv    = (float*)w;  w += (size_t)NN * 4;
    float* rowloss = (float*)w;  w += (size_t)NN * 4;
    float* colsum  = (float*)w;  w += (size_t)BB * 4;
    float* poscol  = (float*)w;  w += (size_t)BB * 4;

    ln_kernel<<<NN, 256, 0, stream>>>(text, tf_t, gamma, beta, qinv);
    ln_vis_kernel<<<BB * LP, 256, 0, stream>>>(vis, vt_t, gamma, beta);

    score_kernel<<<512, 512, 0, stream>>>(tf_t, vt_t, qinv, P_t, numq);
    gram_kernel<<<512, 256, 0, stream>>>(vt_t, G_t);
    den_kernel<<<1024, 256, 0, stream>>>(P_t, G_t, numq, logits);

    loss_row_kernel<<<NN, 64, 0, stream>>>(logits, gm, logtemp, scaled, posv, rowloss);
    colsum_kernel<<<BB, 256, 0, stream>>>(scaled, gm, colsum, poscol);
    final_kernel<<<1, 1024, 0, stream>>>(posv, rowloss, colsum, poscol, gm, out);
}